// Round 11
// baseline (2734.748 us; speedup 1.0000x reference)
//
#include <hip/hip_runtime.h>
#include <hip/hip_bf16.h>
#include <math.h>

typedef unsigned short ushort;
typedef __attribute__((ext_vector_type(8))) short short8;
typedef __attribute__((ext_vector_type(4))) short short4v;
typedef __attribute__((ext_vector_type(4))) float f4v;

constexpr int SEQ = 2048;
constexpr int DM  = 768;
constexpr int NH  = 12;
constexpr int HDM = 64;
constexpr int FF  = 3072;
constexpr int NL  = 12;
constexpr int NV  = 50257;
constexpr int NVP = 50496;   // NV padded to 192

__device__ inline ushort f2bf(float f) {
    union { float f; unsigned u; } v; v.f = f;
    unsigned r = v.u + 0x7fffu + ((v.u >> 16) & 1u);
    return (ushort)(r >> 16);
}

__device__ __forceinline__ void gld16(const ushort* g, ushort* l) {
    __builtin_amdgcn_global_load_lds(
        (const __attribute__((address_space(1))) void*)g,
        (__attribute__((address_space(3))) void*)l, 16, 0, 0);
}

// ---------------- LayerNorm: fp32 in -> bf16 out ----------------
__global__ __launch_bounds__(256) void ln_kernel(const float* __restrict__ x,
                                                 const float* __restrict__ g,
                                                 const float* __restrict__ b,
                                                 ushort* __restrict__ out) {
    int row = blockIdx.x;
    int t = threadIdx.x;
    const float* xr = x + (size_t)row * DM;
    float v0 = xr[t], v1 = xr[t + 256], v2 = xr[t + 512];
    float s = v0 + v1 + v2;
    float s2 = v0 * v0 + v1 * v1 + v2 * v2;
    for (int m = 1; m < 64; m <<= 1) { s += __shfl_xor(s, m); s2 += __shfl_xor(s2, m); }
    __shared__ float ls[4], ls2[4];
    int w = t >> 6;
    if ((t & 63) == 0) { ls[w] = s; ls2[w] = s2; }
    __syncthreads();
    s = ls[0] + ls[1] + ls[2] + ls[3];
    s2 = ls2[0] + ls2[1] + ls2[2] + ls2[3];
    float mu = s * (1.0f / DM);
    float var = s2 * (1.0f / DM) - mu * mu;
    float rs = rsqrtf(var + 1e-5f);
    ushort* o = out + (size_t)row * DM;
    o[t]       = f2bf((v0 - mu) * rs * g[t]       + b[t]);
    o[t + 256] = f2bf((v1 - mu) * rs * g[t + 256] + b[t + 256]);
    o[t + 512] = f2bf((v2 - mu) * rs * g[t + 512] + b[t + 512]);
}

// ------- fused: h += bias + sum(NS split-K partials); hn = LN(h)*g+b --------
template <int NS>
__global__ __launch_bounds__(256) void ln_spk(const float* __restrict__ p,
                                              const float* __restrict__ bias,
                                              float* __restrict__ h,
                                              const float* __restrict__ g,
                                              const float* __restrict__ b,
                                              ushort* __restrict__ out) {
    int row = blockIdx.x;
    int t = threadIdx.x;
    size_t base = (size_t)row * DM;
    float v[3];
    #pragma unroll
    for (int j = 0; j < 3; ++j) {
        int col = t + j * 256;
        float acc = h[base + col] + bias[col];
        #pragma unroll
        for (int s = 0; s < NS; ++s) acc += p[(size_t)s * SEQ * DM + base + col];
        v[j] = acc;
        h[base + col] = acc;
    }
    float s1 = v[0] + v[1] + v[2];
    float s2 = v[0] * v[0] + v[1] * v[1] + v[2] * v[2];
    for (int m = 1; m < 64; m <<= 1) { s1 += __shfl_xor(s1, m); s2 += __shfl_xor(s2, m); }
    __shared__ float ls[4], ls2[4];
    int w = t >> 6;
    if ((t & 63) == 0) { ls[w] = s1; ls2[w] = s2; }
    __syncthreads();
    s1 = ls[0] + ls[1] + ls[2] + ls[3];
    s2 = ls2[0] + ls2[1] + ls2[2] + ls2[3];
    float mu = s1 * (1.0f / DM);
    float var = s2 * (1.0f / DM) - mu * mu;
    float rs = rsqrtf(var + 1e-5f);
    #pragma unroll
    for (int j = 0; j < 3; ++j) {
        int col = t + j * 256;
        out[base + col] = f2bf((v[j] - mu) * rs * g[col] + b[col]);
    }
}

// ---------------- merged transpose-convert: fp32 [K][N] -> bf16 [N][K] -----
struct CvtArgs {
    const float* src[7];
    ushort*      dst[7];
    long inL[7], outL[7];
    int  K[7], N[7], tk[7], tn[7];
    int  base[8];
};

__global__ __launch_bounds__(256) void cvt_all(CvtArgs a) {
    __shared__ ushort T[64][72];
    int idx = blockIdx.x;
    int seg = 0;
    #pragma unroll
    for (int i = 1; i < 7; ++i) if (idx >= a.base[i]) seg = i;
    int local = idx - a.base[seg];
    int K = a.K[seg], N = a.N[seg];
    int tk = a.tk[seg], tn = a.tn[seg];
    int k_t = local % tk;
    int rst = local / tk;
    int n_t = rst % tn;
    int l   = rst / tn;
    const float* ip = a.src[seg] + (size_t)l * a.inL[seg];
    ushort* op      = a.dst[seg] + (size_t)l * a.outL[seg];
    int kb = k_t * 64, nb = n_t * 64;
    int t = threadIdx.x;
    int nl = t & 63, ks = (t >> 6) * 16;
    int n = nb + nl;
    #pragma unroll
    for (int j = 0; j < 16; ++j) {
        float f = (n < N) ? ip[(size_t)(kb + ks + j) * N + n] : 0.f;
        T[nl][ks + j] = f2bf(f);
    }
    __syncthreads();
    int r = t >> 2, c4 = (t & 3) * 16;
    *(short8*)(op + (size_t)(nb + r) * K + kb + c4)     = *(const short8*)&T[r][c4];
    *(short8*)(op + (size_t)(nb + r) * K + kb + c4 + 8) = *(const short8*)&T[r][c4 + 8];
}

// ---------------- GEMM: C[M,N] = A_bf16[M,K] @ Bt_bf16[N,K]^T (+epilogue) --
// EPI 0: bf16 out          EPI 1: fp32 out = acc + bias[col] + res
// EPI 2: bf16 gelu(acc+b)  EPI 3: fp32 out = acc, col<N guarded; z-split via
//                                 blockIdx.z (kOff = z*kLen, out += z*M*ldOut)
// EPI 4: QKV mode: cols<1536 bf16 out; cols>=1536 write V^T to vt[d][m]
// DB: 2-phase double-buffered staging; SWZ: bijective XCD block remap (m204)
template <int BM, int BN, int EPI, bool DB, bool SWZ, int MINW>
__global__ __launch_bounds__(256, MINW) void gemmT(const ushort* __restrict__ A,
                                                   const ushort* __restrict__ Bt,
                                                   const float* __restrict__ bias,
                                                   const float* __restrict__ res,
                                                   void* __restrict__ outp,
                                                   ushort* __restrict__ vt,
                                                   int M, int N, int K,
                                                   int kLen, int ldOut) {
    constexpr int FM = BM / 32;
    constexpr int FN = BN / 32;
    constexpr int NBUF = DB ? 2 : 1;
    constexpr int ASZ = BM * 64;
    constexpr int BSZ = BN * 64;
    __shared__ ushort As[NBUF * ASZ];
    __shared__ ushort Bs[NBUF * BSZ];
    int tid = threadIdx.x, lane = tid & 63, wave = tid >> 6;
    int wm = (wave >> 1) * (BM / 2), wn = (wave & 1) * (BN / 2);
    int mBase, nBase;
    if constexpr (SWZ) {
        int gx = gridDim.x;
        int nwg = gx * gridDim.y;
        int flat = blockIdx.y * gx + blockIdx.x;
        int xcd = flat & 7, idx = flat >> 3;
        int q = nwg >> 3, r = nwg & 7;
        int wg = (xcd < r ? xcd * (q + 1) : r * (q + 1) + (xcd - r) * q) + idx;
        mBase = (wg % gx) * BM;
        nBase = (wg / gx) * BN;
    } else {
        mBase = blockIdx.x * BM;
        nBase = blockIdx.y * BN;
    }
    int kOff = kLen * blockIdx.z;
    int lr = lane & 15, lg = lane >> 4;
    int swz = (lr & 7) << 3;   // element-offset XOR for swizzled reads

    f4v acc[FM][FN];
    #pragma unroll
    for (int i = 0; i < FM; ++i)
        #pragma unroll
        for (int j = 0; j < FN; ++j) acc[i][j] = (f4v){0.f, 0.f, 0.f, 0.f};

    int cBase = wave * 64 + lane;

    auto stage = [&](int kb, int buf) {
        #pragma unroll
        for (int i = 0; i < BM / 32; ++i) {
            int c = i * 256 + cBase;
            int row = c >> 3;
            int kc = (c & 7) ^ (row & 7);     // inverse-swizzled source
            gld16(A + (size_t)(mBase + row) * K + kOff + kb + kc * 8,
                  As + buf * ASZ + (size_t)(i * 256 + wave * 64) * 8);
        }
        #pragma unroll
        for (int i = 0; i < BN / 32; ++i) {
            int c = i * 256 + cBase;
            int row = c >> 3;
            int kc = (c & 7) ^ (row & 7);
            gld16(Bt + (size_t)(nBase + row) * K + kOff + kb + kc * 8,
                  Bs + buf * BSZ + (size_t)(i * 256 + wave * 64) * 8);
        }
    };
    auto compute = [&](int buf) {
        #pragma unroll
        for (int kk = 0; kk < 2; ++kk) {
            short8 a[FM], b[FN];
            #pragma unroll
            for (int fr = 0; fr < FM; ++fr)
                a[fr] = *(const short8*)(As + buf * ASZ + (wm + fr * 16 + lr) * 64 + ((((kk * 4 + lg) << 3)) ^ swz));
            #pragma unroll
            for (int fc = 0; fc < FN; ++fc)
                b[fc] = *(const short8*)(Bs + buf * BSZ + (wn + fc * 16 + lr) * 64 + ((((kk * 4 + lg) << 3)) ^ swz));
            #pragma unroll
            for (int fr = 0; fr < FM; ++fr)
                #pragma unroll
                for (int fc = 0; fc < FN; ++fc)
                    acc[fr][fc] = __builtin_amdgcn_mfma_f32_16x16x32_bf16(a[fr], b[fc], acc[fr][fc], 0, 0, 0);
        }
    };

    if constexpr (DB) {
        stage(0, 0);
        __syncthreads();
        int cur = 0;
        for (int kb = 0; kb < kLen; kb += 64) {
            if (kb + 64 < kLen) stage(kb + 64, cur ^ 1);   // prefetch next tile
            compute(cur);
            __syncthreads();    // readers of cur done + prefetch drained
            cur ^= 1;
        }
    } else {
        for (int kb = 0; kb < kLen; kb += 64) {
            stage(kb, 0);
            __syncthreads();
            compute(0);
            __syncthreads();
        }
    }

    if constexpr (EPI == 4) {
        if (nBase < 1536) {
            #pragma unroll
            for (int fr = 0; fr < FM; ++fr)
                #pragma unroll
                for (int fc = 0; fc < FN; ++fc)
                    #pragma unroll
                    for (int r = 0; r < 4; ++r) {
                        int row = mBase + wm + fr * 16 + 4 * lg + r;
                        int col = nBase + wn + fc * 16 + lr;
                        ((ushort*)outp)[(size_t)row * ldOut + col] = f2bf(acc[fr][fc][r]);
                    }
        } else {
            // V block: write V^T[d][m], d = col-1536, packed 4 bf16 (m contiguous)
            #pragma unroll
            for (int fr = 0; fr < FM; ++fr)
                #pragma unroll
                for (int fc = 0; fc < FN; ++fc) {
                    short4v pk;
                    #pragma unroll
                    for (int r = 0; r < 4; ++r) pk[r] = (short)f2bf(acc[fr][fc][r]);
                    int d  = nBase - 1536 + wn + fc * 16 + lr;
                    int m0 = mBase + wm + fr * 16 + 4 * lg;
                    *(short4v*)(vt + (size_t)d * SEQ + m0) = pk;
                }
        }
        return;
    }

    float* out3 = (float*)outp;
    if constexpr (EPI == 3) out3 += (size_t)blockIdx.z * M * ldOut;

    #pragma unroll
    for (int fr = 0; fr < FM; ++fr)
        #pragma unroll
        for (int fc = 0; fc < FN; ++fc)
            #pragma unroll
            for (int r = 0; r < 4; ++r) {
                int row = mBase + wm + fr * 16 + 4 * lg + r;
                int col = nBase + wn + fc * 16 + lr;
                float v = acc[fr][fc][r];
                if constexpr (EPI == 0) {
                    ((ushort*)outp)[(size_t)row * ldOut + col] = f2bf(v);
                } else if constexpr (EPI == 1) {
                    v += bias[col] + res[(size_t)row * ldOut + col];
                    ((float*)outp)[(size_t)row * ldOut + col] = v;
                } else if constexpr (EPI == 2) {
                    v += bias[col];
                    v = 0.5f * v * (1.f + erff(v * 0.70710678118f));
                    ((ushort*)outp)[(size_t)row * ldOut + col] = f2bf(v);
                } else {
                    if (col < N) out3[(size_t)row * ldOut + col] = v;
                }
            }
}

// ---------------- Flash attention v8: 2 waves x 32 q-rows (64 q-rows/block),
// K/V frags reused across both q-frags; DB staging via global_load_lds,
// XOR-swizzled LDS, full barriers (replay-safe). --------------------------
__global__ __launch_bounds__(128) void attn_v8(const ushort* __restrict__ Qg,
                                               const ushort* __restrict__ Kg,
                                               const ushort* __restrict__ Vt,
                                               ushort* __restrict__ Og) {
    __shared__ ushort Ks[2 * 4096];    // 2 x [64 krow][64 d swizzled]
    __shared__ ushort Vs[2 * 4096];    // 2 x [64 d][64 m swizzled]
    __shared__ ushort Ps[4 * 1024];    // per (wave,frag) [16 qrow][64 k swizzled]
    int tid = threadIdx.x, lane = tid & 63, wave = tid >> 6;
    int flat = blockIdx.x;
    int qt   = (SEQ / 64) - 1 - (flat / NH);   // longest q-tiles first
    int head = flat % NH;
    int lr = lane & 15, lg = lane >> 4;
    int qr0 = qt * 64 + wave * 32;
    int hoff = head * HDM;
    int swz = (lr & 7) << 3;
    int ktiles = qt + 1;

    short8 qf[2][2];
    #pragma unroll
    for (int f = 0; f < 2; ++f) {
        const ushort* qr = Qg + (size_t)(qr0 + f * 16 + lr) * 2304 + hoff;
        qf[f][0] = *(const short8*)(qr + lg * 8);
        qf[f][1] = *(const short8*)(qr + 32 + lg * 8);
    }

    const f4v fz = {0.f, 0.f, 0.f, 0.f};
    f4v o[2][4];
    float mrow[2][4], lsum[2][4];
    #pragma unroll
    for (int f = 0; f < 2; ++f)
        #pragma unroll
        for (int r = 0; r < 4; ++r) {
            o[f][r] = fz; mrow[f][r] = -1e30f; lsum[f][r] = 0.f;
        }

    auto stageKV = [&](int kb, int buf) {
        #pragma unroll
        for (int j = 0; j < 4; ++j) {
            int cc = j * 128 + wave * 64 + lane;
            int row = cc >> 3;
            int kc = (cc & 7) ^ (row & 7);
            gld16(Kg + (size_t)(kb * 64 + row) * 2304 + hoff + kc * 8,
                  Ks + buf * 4096 + (size_t)(j * 128 + wave * 64) * 8);
            gld16(Vt + (size_t)(hoff + row) * SEQ + kb * 64 + kc * 8,
                  Vs + buf * 4096 + (size_t)(j * 128 + wave * 64) * 8);
        }
    };

    stageKV(0, 0);
    __syncthreads();
    int cur = 0;

    for (int kb = 0; kb < ktiles; ++kb) {
        if (kb + 1 < ktiles) stageKV(kb + 1, cur ^ 1);   // prefetch next K/V tile

        // load K frags once, reuse for both q-frags
        short8 k0[4], k1[4];
        #pragma unroll
        for (int n = 0; n < 4; ++n) {
            const ushort* kr = Ks + cur * 4096 + (n * 16 + lr) * 64;
            k0[n] = *(const short8*)(kr + ((lg << 3) ^ swz));
            k1[n] = *(const short8*)(kr + ((((4 + lg) << 3)) ^ swz));
        }

        // S = Q K^T for both frags
        f4v s[2][4];
        #pragma unroll
        for (int f = 0; f < 2; ++f)
            #pragma unroll
            for (int n = 0; n < 4; ++n) {
                f4v z = fz;
                z = __builtin_amdgcn_mfma_f32_16x16x32_bf16(qf[f][0], k0[n], z, 0, 0, 0);
                s[f][n] = __builtin_amdgcn_mfma_f32_16x16x32_bf16(qf[f][1], k1[n], z, 0, 0, 0);
            }
        if (kb == ktiles - 1) {
            #pragma unroll
            for (int f = 0; f < 2; ++f)
                #pragma unroll
                for (int n = 0; n < 4; ++n)
                    #pragma unroll
                    for (int r = 0; r < 4; ++r) {
                        int col = kb * 64 + n * 16 + lr;
                        int row = qr0 + f * 16 + 4 * lg + r;
                        if (col > row) s[f][n][r] = -1e38f;
                    }
        }

        // online softmax; P -> per-(wave,frag) swizzled LDS
        int sub = lr & 7, hi = lr >> 3;
        #pragma unroll
        for (int f = 0; f < 2; ++f)
            #pragma unroll
            for (int r = 0; r < 4; ++r) {
                float mx = fmaxf(fmaxf(s[f][0][r], s[f][1][r]), fmaxf(s[f][2][r], s[f][3][r]));
                mx = fmaxf(mx, __shfl_xor(mx, 1));
                mx = fmaxf(mx, __shfl_xor(mx, 2));
                mx = fmaxf(mx, __shfl_xor(mx, 4));
                mx = fmaxf(mx, __shfl_xor(mx, 8));
                float mnew = fmaxf(mrow[f][r], mx);
                float corr = __expf(mrow[f][r] - mnew);
                float ps0 = __expf(s[f][0][r] - mnew);
                float ps1 = __expf(s[f][1][r] - mnew);
                float ps2 = __expf(s[f][2][r] - mnew);
                float ps3 = __expf(s[f][3][r] - mnew);
                float rs = ps0 + ps1 + ps2 + ps3;
                rs += __shfl_xor(rs, 1);
                rs += __shfl_xor(rs, 2);
                rs += __shfl_xor(rs, 4);
                rs += __shfl_xor(rs, 8);
                lsum[f][r] = lsum[f][r] * corr + rs;
                mrow[f][r] = mnew;
                o[f][0][r] *= corr; o[f][1][r] *= corr; o[f][2][r] *= corr; o[f][3][r] *= corr;
                int prow = 4 * lg + r;
                ushort* pb = Ps + (wave * 2 + f) * 1024 + prow * 64;
                int px = prow & 7;
                pb[(((0 + hi) ^ px) << 3) | sub] = f2bf(ps0);
                pb[(((2 + hi) ^ px) << 3) | sub] = f2bf(ps1);
                pb[(((4 + hi) ^ px) << 3) | sub] = f2bf(ps2);
                pb[(((6 + hi) ^ px) << 3) | sub] = f2bf(ps3);
            }
        __syncthreads();   // P ready (also drains prefetch vmcnt)

        // O += P V (V frags reused across both q-frags)
        #pragma unroll
        for (int kk = 0; kk < 2; ++kk) {
            short8 pa[2];
            #pragma unroll
            for (int f = 0; f < 2; ++f)
                pa[f] = *(const short8*)(Ps + (wave * 2 + f) * 1024 + lr * 64 + ((((kk * 4 + lg) << 3)) ^ swz));
            #pragma unroll
            for (int dn = 0; dn < 4; ++dn) {
                short8 vb = *(const short8*)(Vs + cur * 4096 + (dn * 16 + lr) * 64 + ((((kk * 4 + lg) << 3)) ^ swz));
                #pragma unroll
                for (int f = 0; f < 2; ++f)
                    o[f][dn] = __builtin_amdgcn_mfma_f32_16x16x32_bf16(pa[f], vb, o[f][dn], 0, 0, 0);
            }
        }
        __syncthreads();   // readers of cur/Ps done before overwrite
        cur ^= 1;
    }

    #pragma unroll
    for (int f = 0; f < 2; ++f)
        #pragma unroll
        for (int dn = 0; dn < 4; ++dn)
            #pragma unroll
            for (int r = 0; r < 4; ++r) {
                int row = qr0 + f * 16 + 4 * lg + r;
                Og[(size_t)row * DM + hoff + dn * 16 + lr] = f2bf(o[f][dn][r] / lsum[f][r]);
            }
}

// ---------------- fallback-path kernels (round-1 style) --------------------
template <int EPI>
__global__ __launch_bounds__(256) void gemm64(const ushort* __restrict__ A,
                                              const float* __restrict__ B,
                                              const float* __restrict__ bias,
                                              const float* __restrict__ res,
                                              void* __restrict__ outp,
                                              int M, int N, int K) {
    __shared__ ushort As[64][64];
    __shared__ ushort Bs[64][72];
    int tid = threadIdx.x;
    int lane = tid & 63, wave = tid >> 6;
    int wm = (wave >> 1) * 32, wn = (wave & 1) * 32;
    int mBase = blockIdx.x * 64, nBase = blockIdx.y * 64;
    int lr = lane & 15, lg = lane >> 4;

    const f4v fz = {0.f, 0.f, 0.f, 0.f};
    f4v acc[2][2];
    acc[0][0] = fz; acc[0][1] = fz; acc[1][0] = fz; acc[1][1] = fz;

    int ar = tid >> 2, ac = (tid & 3) * 16;
    int br = tid >> 2, bc = (tid & 3) * 16;

    for (int kb = 0; kb < K; kb += 64) {
        const short8* ag = (const short8*)(A + (size_t)(mBase + ar) * K + kb + ac);
        *(short8*)&As[ar][ac]     = ag[0];
        *(short8*)&As[ar][ac + 8] = ag[1];
        if constexpr (EPI == 3) {
            #pragma unroll
            for (int j = 0; j < 16; ++j) {
                int col = nBase + bc + j;
                float f = (col < N) ? B[(size_t)(kb + br) * N + col] : 0.f;
                Bs[bc + j][br] = f2bf(f);
            }
        } else {
            const float4* bg = (const float4*)(B + (size_t)(kb + br) * N + nBase + bc);
            float fv[16];
            *(float4*)&fv[0]  = bg[0];
            *(float4*)&fv[4]  = bg[1];
            *(float4*)&fv[8]  = bg[2];
            *(float4*)&fv[12] = bg[3];
            #pragma unroll
            for (int j = 0; j < 16; ++j) Bs[bc + j][br] = f2bf(fv[j]);
        }
        __syncthreads();
        #pragma unroll
        for (int kk = 0; kk < 2; ++kk) {
            short8 a0 = *(const short8*)&As[wm + lr][kk * 32 + lg * 8];
            short8 a1 = *(const short8*)&As[wm + 16 + lr][kk * 32 + lg * 8];
            short8 b0 = *(const short8*)&Bs[wn + lr][kk * 32 + lg * 8];
            short8 b1 = *(const short8*)&Bs[wn + 16 + lr][kk * 32 + lg * 8];
            acc[0][0] = __builtin_amdgcn_mfma_f32_16x16x32_bf16(a0, b0, acc[0][0], 0, 0, 0);
            acc[0][1] = __builtin_amdgcn_mfma_f32_16x16x32_bf16(a0, b1, acc[0][1], 0, 0, 0);
            acc[1][0] = __builtin_amdgcn_mfma_f32_16x16x32_bf16(a1, b0, acc[1][0], 0, 0, 0);
            acc[1][1] = __builtin_amdgcn_mfma_f32_16x16x32_bf16(a1, b1, acc[1][1], 0, 0, 0);
        }
        __syncthreads();
    }

    #pragma unroll
    for (int fm = 0; fm < 2; ++fm)
        #pragma unroll
        for (int fn = 0; fn < 2; ++fn)
            #pragma unroll
            for (int r = 0; r < 4; ++r) {
                int row = mBase + wm + fm * 16 + 4 * lg + r;
                int col = nBase + wn + fn * 16 + lr;
                float v = acc[fm][fn][r];
                if constexpr (EPI == 0) {
                    ((ushort*)outp)[(size_t)row * N + col] = f2bf(v);
                } else if constexpr (EPI == 1) {
                    v += bias[col] + res[(size_t)row * N + col];
                    ((float*)outp)[(size_t)row * N + col] = v;
                } else if constexpr (EPI == 2) {
                    v += bias[col];
                    v = 0.5f * v * (1.f + erff(v * 0.70710678118f));
                    ((ushort*)outp)[(size_t)row * N + col] = f2bf(v);
                } else {
                    if (col < N) ((float*)outp)[(size_t)row * N + col] = v;
                }
            }
}

__global__ __launch_bounds__(256) void attn_stage(const ushort* __restrict__ Qg,
                                                  const ushort* __restrict__ Kg,
                                                  const ushort* __restrict__ Vg,
                                                  ushort* __restrict__ Og,
                                                  int ld) {
    __shared__ ushort Ks[64][64];
    __shared__ ushort Vs[64][72];
    __shared__ ushort Ps[4][16][64];
    int tid = threadIdx.x, lane = tid & 63, wave = tid >> 6;
    int qb = blockIdx.x, head = blockIdx.y;
    int lr = lane & 15, lg = lane >> 4;
    int qr0 = qb * 64 + wave * 16;
    size_t hoff = (size_t)head * HDM;

    short8 qf0 = *(const short8*)(Qg + (size_t)(qr0 + lr) * ld + hoff + lg * 8);
    short8 qf1 = *(const short8*)(Qg + (size_t)(qr0 + lr) * ld + hoff + 32 + lg * 8);

    const f4v fz = {0.f, 0.f, 0.f, 0.f};
    f4v o[4];
    o[0] = fz; o[1] = fz; o[2] = fz; o[3] = fz;
    float mrow[4] = {-1e30f, -1e30f, -1e30f, -1e30f};
    float lsum[4] = {0.f, 0.f, 0.f, 0.f};

    int r_ = tid >> 2, c_ = (tid & 3) * 16;

    for (int kb = 0; kb <= qb; ++kb) {
        const short8* kg = (const short8*)(Kg + (size_t)(kb * 64 + r_) * ld + hoff + c_);
        *(short8*)&Ks[r_][c_]     = kg[0];
        *(short8*)&Ks[r_][c_ + 8] = kg[1];
        const short8* vg = (const short8*)(Vg + (size_t)(kb * 64 + r_) * ld + hoff + c_);
        short8 v0 = vg[0], v1 = vg[1];
        #pragma unroll
        for (int j = 0; j < 8; ++j) {
            Vs[c_ + j][r_]     = (ushort)v0[j];
            Vs[c_ + 8 + j][r_] = (ushort)v1[j];
        }
        __syncthreads();

        f4v s[4];
        #pragma unroll
        for (int n = 0; n < 4; ++n) {
            short8 k0 = *(const short8*)&Ks[n * 16 + lr][lg * 8];
            short8 k1 = *(const short8*)&Ks[n * 16 + lr][32 + lg * 8];
            f4v z = fz;
            z = __builtin_amdgcn_mfma_f32_16x16x32_bf16(qf0, k0, z, 0, 0, 0);
            s[n] = __builtin_amdgcn_mfma_f32_16x16x32_bf16(qf1, k1, z, 0, 0, 0);
        }
        if (kb == qb) {
            #pragma unroll
            for (int n = 0; n < 4; ++n)
                #pragma unroll
                for (int r = 0; r < 4; ++r) {
                    int col = kb * 64 + n * 16 + lr;
                    int row = qr0 + 4 * lg + r;
                    if (col > row) s[n][r] = -1e38f;
                }
        }

        #pragma unroll
        for (int r = 0; r < 4; ++r) {
            float mx = fmaxf(fmaxf(s[0][r], s[1][r]), fmaxf(s[2][r], s[3][r]));
            mx = fmaxf(mx, __shfl_xor(mx, 1));
            mx = fmaxf(mx, __shfl_xor(mx, 2));
            mx = fmaxf(mx, __shfl_xor(mx, 4));
            mx = fmaxf(mx, __shfl_xor(mx, 8));
            float mnew = fmaxf(mrow[r], mx);
            float corr = __expf(mrow[r] - mnew);
            float ps0 = __expf(s[0][r] - mnew);
            float ps1 = __expf(s[1][r] - mnew);
            float ps2 = __expf(s[2][r] - mnew);
            float ps3 = __expf(s[3][r] - mnew);
            float rs = ps0 + ps1 + ps2 + ps3;
            rs += __shfl_xor(rs, 1);
            rs += __shfl_xor(rs, 2);
            rs += __shfl_xor(rs, 4);
            rs += __shfl_xor(rs, 8);
            lsum[r] = lsum[r] * corr + rs;
            mrow[r] = mnew;
            o[0][r] *= corr; o[1][r] *= corr; o[2][r] *= corr; o[3][r] *= corr;
            Ps[wave][4 * lg + r][0 * 16 + lr] = f2bf(ps0);
            Ps[wave][4 * lg + r][1 * 16 + lr] = f2bf(ps1);
            Ps[wave][4 * lg + r][2 * 16 + lr] = f2bf(ps2);
            Ps[wave][4 * lg + r][3 * 16 + lr] = f2bf(ps3);
        }
        __syncthreads();

        #pragma unroll
        for (int kk = 0; kk < 2; ++kk) {
            short8 pa = *(const short8*)&Ps[wave][lr][kk * 32 + lg * 8];
            #pragma unroll
            for (int dn = 0; dn < 4; ++dn) {
                short8 vb = *(const short8*)&Vs[dn * 16 + lr][kk * 32 + lg * 8];
                o[dn] = __builtin_amdgcn_mfma_f32_16x16x32_bf16(pa, vb, o[dn], 0, 0, 0);
            }
        }
        __syncthreads();
    }

    #pragma unroll
    for (int dn = 0; dn < 4; ++dn)
        #pragma unroll
        for (int r = 0; r < 4; ++r) {
            int row = qr0 + 4 * lg + r;
            Og[(size_t)row * DM + hoff + dn * 16 + lr] = f2bf(o[dn][r] / lsum[r]);
        }
}

extern "C" void kernel_launch(void* const* d_in, const int* in_sizes, int n_in,
                              void* d_out, int out_size, void* d_ws, size_t ws_size,
                              hipStream_t stream) {
    const float* x     = (const float*)d_in[0];
    const float* ln1_g = (const float*)d_in[1];
    const float* ln1_b = (const float*)d_in[2];
    const float* Wq    = (const float*)d_in[3];
    const float* Wk    = (const float*)d_in[4];
    const float* Wv    = (const float*)d_in[5];
    const float* Wo    = (const float*)d_in[6];
    const float* bo    = (const float*)d_in[7];
    const float* ln2_g = (const float*)d_in[8];
    const float* ln2_b = (const float*)d_in[9];
    const float* Wfc   = (const float*)d_in[10];
    const float* bfc   = (const float*)d_in[11];
    const float* Wp    = (const float*)d_in[12];
    const float* bp    = (const float*)d_in[13];
    const float* lnf_g = (const float*)d_in[14];
    const float* lnf_b = (const float*)d_in[15];
    const float* Wlm   = (const float*)d_in[16];

    dim3 blk(256);

    // ---- workspace layout (new path) ----
    size_t offs[13];
    size_t need = 0;
    size_t sizes[12] = {
        (size_t)SEQ * DM * 4,          // h (fp32)
        (size_t)SEQ * DM * 2,          // hn
        (size_t)SEQ * 2304 * 2,        // qkv packed
        (size_t)SEQ * DM * 2,          // ab
        (size_t)SEQ * FF * 2,          // fb
        (size_t)DM * SEQ * 2,          // vT [768][2048]
        (size_t)NL * 2304 * DM * 2,    // qkvw^T packed
        (size_t)NL * DM * DM * 2,      // Wo^T
        (size_t)NL * FF * DM * 2,      // Wfc^T
        (size_t)NL * DM * FF * 2,      // Wp^T
        (size_t)NVP * DM * 2,          // Wlm^T [50496][768]
        (size_t)4 * SEQ * DM * 4,      // spk: split-K partials (25 MB)
    };
    for (int i = 0; i < 12; ++i) { offs[i] = need; need += sizes[i]; }
    offs[12] = need;
    size_t need_base = offs[11];       // without spk
    bool useSpk = (ws_size >= need);

    if (ws_size >= need_base) {
        char* ws = (char*)d_ws;
        float*  h    = (float*)(ws + offs[0]);
        ushort* hn   = (ushort*)(ws + offs[1]);
        ushort* qkv  = (ushort*)(ws + offs[2]);
        ushort* ab_  = (ushort*)(ws + offs[3]);
        ushort* fb_  = (ushort*)(ws + offs[4]);
        ushort* vt   = (ushort*)(ws + offs[5]);
        ushort* qkvw = (ushort*)(ws + offs[6]);
        ushort* wow  = (ushort*)(ws + offs[7]);
        ushort* fcw  = (ushort*)(ws + offs[8]);
        ushort* wpw  = (ushort*)(ws + offs[9]);
        ushort* lmw  = (ushort*)(ws + offs[10]);
        float*  spk  = (float*)(ws + offs[11]);

        hipMemcpyAsync(h, x, (size_t)SEQ * DM * 4, hipMemcpyDeviceToDevice, stream);

        // ---- single merged weight-conversion dispatch ----
        CvtArgs ca;
        const float* srcs[7] = {Wq, Wk, Wv, Wo, Wfc, Wp, Wlm};
        ushort* dsts[7] = {qkvw, qkvw + DM * DM, qkvw + 2 * DM * DM, wow, fcw, wpw, lmw};
        long inLs[7]  = {(long)DM * DM, (long)DM * DM, (long)DM * DM, (long)DM * DM,
                         (long)DM * FF, (long)FF * DM, 0};
        long outLs[7] = {(long)2304 * DM, (long)2304 * DM, (long)2304 * DM, (long)DM * DM,
                         (long)FF * DM, (long)DM * FF, 0};
        int Ks_[7] = {DM, DM, DM, DM, DM, FF, DM};
        int Ns_[7] = {DM, DM, DM, DM, FF, DM, NV};
        int tks[7] = {12, 12, 12, 12, 12, 48, 12};
        int tns[7] = {12, 12, 12, 12, 48, 12, NVP / 64};
        int lays[7] = {NL, NL, NL, NL, NL, NL, 1};
        int total = 0;
        for (int i = 0; i < 7; ++i) {
            ca.src[i] = srcs[i]; ca.dst[i] = dsts[i];
            ca.inL[i] = inLs[i]; ca.outL[i] = outLs[i];
            ca.K[i] = Ks_[i]; ca.N[i] = Ns_[i]; ca.tk[i] = tks[i]; ca.tn[i] = tns[i];
            ca.base[i] = total;
            total += tks[i] * tns[i] * lays[i];
        }
        ca.base[7] = total;
        cvt_all<<<dim3(total), blk, 0, stream>>>(ca);

        ln_kernel<<<SEQ, blk, 0, stream>>>(h, ln1_g, ln1_b, hn);
        for (int l = 0; l < NL; ++l) {
            const ushort* qw = qkvw + (size_t)l * 2304 * DM;
            gemmT<64, 64, 4, true, false, 2><<<dim3(32, 36), blk, 0, stream>>>(hn, qw, nullptr, nullptr, qkv, vt, SEQ, 2304, DM, DM, 2304);
            attn_v8<<<dim3((SEQ / 64) * NH), dim3(128), 0, stream>>>(qkv, qkv + 768, vt, ab_);
            if (useSpk) {
                gemmT<64, 64, 3, true, false, 2><<<dim3(32, 12, 2), blk, 0, stream>>>(ab_, wow + (size_t)l * DM * DM, nullptr, nullptr, spk, nullptr, SEQ, DM, DM, DM / 2, DM);
                ln_spk<2><<<SEQ, blk, 0, stream>>>(spk, bo + l * DM, h, ln2_g + l * DM, ln2_b + l * DM, hn);
            } else {
                gemmT<64, 64, 1, true, false, 2><<<dim3(32, 12), blk, 0, stream>>>(ab_, wow + (size_t)l * DM * DM, bo + l * DM, h, h, nullptr, SEQ, DM, DM, DM, DM);
                ln_kernel<<<SEQ, blk, 0, stream>>>(h, ln2_g + l * DM, ln2_b + l * DM, hn);
            }
            gemmT<64, 64, 2, true, false, 2><<<dim3(32, 48), blk, 0, stream>>>(hn, fcw + (size_t)l * FF * DM, bfc + l * FF, nullptr, fb_, nullptr, SEQ, FF, DM, DM, FF);
            const float* g2 = (l + 1 < NL) ? ln1_g + (l + 1) * DM : lnf_g;
            const float* b2 = (l + 1 < NL) ? ln1_b + (l + 1) * DM : lnf_b;
            if (useSpk) {
                gemmT<64, 64, 3, true, false, 2><<<dim3(32, 12, 4), blk, 0, stream>>>(fb_, wpw + (size_t)l * DM * FF, nullptr, nullptr, spk, nullptr, SEQ, DM, FF, FF / 4, DM);
                ln_spk<4><<<SEQ, blk, 0, stream>>>(spk, bp + l * DM, h, g2, b2, hn);
            } else {
                gemmT<64, 64, 1, true, false, 2><<<dim3(32, 12), blk, 0, stream>>>(fb_, wpw + (size_t)l * DM * FF, bp + l * DM, h, h, nullptr, SEQ, DM, FF, FF, DM);
                ln_kernel<<<SEQ, blk, 0, stream>>>(h, g2, b2, hn);
            }
        }
        gemmT<128, 192, 3, false, true, 3><<<dim3(16, NVP / 192), blk, 0, stream>>>(hn, lmw, nullptr, nullptr, d_out, nullptr, SEQ, NV, DM, DM, NV);
        return;
    }

    // ---------------- fallback: round-1 path (fp32-B GEMMs) ----------------
    char* ws = (char*)d_ws;
    float*  h   = (float*)ws;   ws += (size_t)SEQ * DM * 4;
    ushort* hn  = (ushort*)ws;  ws += (size_t)SEQ * DM * 2;
    ushort* qb_ = (ushort*)ws;  ws += (size_t)SEQ * DM * 2;
    ushort* kb_ = (ushort*)ws;  ws += (size_t)SEQ * DM * 2;
    ushort* vb_ = (ushort*)ws;  ws += (size_t)SEQ * DM * 2;
    ushort* ab_ = (ushort*)ws;  ws += (size_t)SEQ * DM * 2;
    ushort* fb_ = (ushort*)ws;  ws += (size_t)SEQ * FF * 2;

    hipMemcpyAsync(h, x, (size_t)SEQ * DM * 4, hipMemcpyDeviceToDevice, stream);

    dim3 gdd(SEQ / 64, DM / 64);
    dim3 gdf(SEQ / 64, FF / 64);
    dim3 gda(SEQ / 64, NH);
    dim3 gdl(SEQ / 64, (NV + 63) / 64);

    for (int l = 0; l < NL; ++l) {
        ln_kernel<<<SEQ, blk, 0, stream>>>(h, ln1_g + l * DM, ln1_b + l * DM, hn);
        gemm64<0><<<gdd, blk, 0, stream>>>(hn, Wq + (size_t)l * DM * DM, nullptr, nullptr, qb_, SEQ, DM, DM);
        gemm64<0><<<gdd, blk, 0, stream>>>(hn, Wk + (size_t)l * DM * DM, nullptr, nullptr, kb_, SEQ, DM, DM);
        gemm64<0><<<gdd, blk, 0, stream>>>(hn, Wv + (size_t)l * DM * DM, nullptr, nullptr, vb_, SEQ, DM, DM);
        attn_stage<<<gda, blk, 0, stream>>>(qb_, kb_, vb_, ab_, DM);
        gemm64<1><<<gdd, blk, 0, stream>>>(ab_, Wo + (size_t)l * DM * DM, bo + l * DM, h, h, SEQ, DM, DM);
        ln_kernel<<<SEQ, blk, 0, stream>>>(h, ln2_g + l * DM, ln2_b + l * DM, hn);
        gemm64<2><<<gdf, blk, 0, stream>>>(hn, Wfc + (size_t)l * DM * FF, bfc + l * FF, nullptr, fb_, SEQ, FF, DM);
        gemm64<1><<<gdd, blk, 0, stream>>>(fb_, Wp + (size_t)l * FF * DM, bp + l * DM, h, h, SEQ, DM, FF);
    }
    ln_kernel<<<SEQ, blk, 0, stream>>>(h, lnf_g, lnf_b, hn);
    gemm64<3><<<gdl, blk, 0, stream>>>(hn, Wlm, nullptr, nullptr, d_out, SEQ, NV, DM);
}

// Round 12
// 2357.104 us; speedup vs baseline: 1.1602x; 1.1602x over previous
//
#include <hip/hip_runtime.h>
#include <hip/hip_bf16.h>
#include <math.h>

typedef unsigned short ushort;
typedef __attribute__((ext_vector_type(8))) short short8;
typedef __attribute__((ext_vector_type(4))) short short4v;
typedef __attribute__((ext_vector_type(4))) float f4v;

constexpr int SEQ = 2048;
constexpr int DM  = 768;
constexpr int NH  = 12;
constexpr int HDM = 64;
constexpr int FF  = 3072;
constexpr int NL  = 12;
constexpr int NV  = 50257;
constexpr int NVP = 50496;   // NV padded to 192

__device__ inline ushort f2bf(float f) {
    union { float f; unsigned u; } v; v.f = f;
    unsigned r = v.u + 0x7fffu + ((v.u >> 16) & 1u);
    return (ushort)(r >> 16);
}

__device__ __forceinline__ void gld16(const ushort* g, ushort* l) {
    __builtin_amdgcn_global_load_lds(
        (const __attribute__((address_space(1))) void*)g,
        (__attribute__((address_space(3))) void*)l, 16, 0, 0);
}

// ---------------- LayerNorm: fp32 in -> bf16 out ----------------
__global__ __launch_bounds__(256) void ln_kernel(const float* __restrict__ x,
                                                 const float* __restrict__ g,
                                                 const float* __restrict__ b,
                                                 ushort* __restrict__ out) {
    int row = blockIdx.x;
    int t = threadIdx.x;
    const float* xr = x + (size_t)row * DM;
    float v0 = xr[t], v1 = xr[t + 256], v2 = xr[t + 512];
    float s = v0 + v1 + v2;
    float s2 = v0 * v0 + v1 * v1 + v2 * v2;
    for (int m = 1; m < 64; m <<= 1) { s += __shfl_xor(s, m); s2 += __shfl_xor(s2, m); }
    __shared__ float ls[4], ls2[4];
    int w = t >> 6;
    if ((t & 63) == 0) { ls[w] = s; ls2[w] = s2; }
    __syncthreads();
    s = ls[0] + ls[1] + ls[2] + ls[3];
    s2 = ls2[0] + ls2[1] + ls2[2] + ls2[3];
    float mu = s * (1.0f / DM);
    float var = s2 * (1.0f / DM) - mu * mu;
    float rs = rsqrtf(var + 1e-5f);
    ushort* o = out + (size_t)row * DM;
    o[t]       = f2bf((v0 - mu) * rs * g[t]       + b[t]);
    o[t + 256] = f2bf((v1 - mu) * rs * g[t + 256] + b[t + 256]);
    o[t + 512] = f2bf((v2 - mu) * rs * g[t + 512] + b[t + 512]);
}

// ------- fused: h += bias + sum(NS split-K partials); hn = LN(h)*g+b --------
template <int NS>
__global__ __launch_bounds__(256) void ln_spk(const float* __restrict__ p,
                                              const float* __restrict__ bias,
                                              float* __restrict__ h,
                                              const float* __restrict__ g,
                                              const float* __restrict__ b,
                                              ushort* __restrict__ out) {
    int row = blockIdx.x;
    int t = threadIdx.x;
    size_t base = (size_t)row * DM;
    float v[3];
    #pragma unroll
    for (int j = 0; j < 3; ++j) {
        int col = t + j * 256;
        float acc = h[base + col] + bias[col];
        #pragma unroll
        for (int s = 0; s < NS; ++s) acc += p[(size_t)s * SEQ * DM + base + col];
        v[j] = acc;
        h[base + col] = acc;
    }
    float s1 = v[0] + v[1] + v[2];
    float s2 = v[0] * v[0] + v[1] * v[1] + v[2] * v[2];
    for (int m = 1; m < 64; m <<= 1) { s1 += __shfl_xor(s1, m); s2 += __shfl_xor(s2, m); }
    __shared__ float ls[4], ls2[4];
    int w = t >> 6;
    if ((t & 63) == 0) { ls[w] = s1; ls2[w] = s2; }
    __syncthreads();
    s1 = ls[0] + ls[1] + ls[2] + ls[3];
    s2 = ls2[0] + ls2[1] + ls2[2] + ls2[3];
    float mu = s1 * (1.0f / DM);
    float var = s2 * (1.0f / DM) - mu * mu;
    float rs = rsqrtf(var + 1e-5f);
    #pragma unroll
    for (int j = 0; j < 3; ++j) {
        int col = t + j * 256;
        out[base + col] = f2bf((v[j] - mu) * rs * g[col] + b[col]);
    }
}

// ---------------- merged transpose-convert: fp32 [K][N] -> bf16 [N][K] -----
struct CvtArgs {
    const float* src[7];
    ushort*      dst[7];
    long inL[7], outL[7];
    int  K[7], N[7], tk[7], tn[7];
    int  base[8];
};

__global__ __launch_bounds__(256) void cvt_all(CvtArgs a) {
    __shared__ ushort T[64][72];
    int idx = blockIdx.x;
    int seg = 0;
    #pragma unroll
    for (int i = 1; i < 7; ++i) if (idx >= a.base[i]) seg = i;
    int local = idx - a.base[seg];
    int K = a.K[seg], N = a.N[seg];
    int tk = a.tk[seg], tn = a.tn[seg];
    int k_t = local % tk;
    int rst = local / tk;
    int n_t = rst % tn;
    int l   = rst / tn;
    const float* ip = a.src[seg] + (size_t)l * a.inL[seg];
    ushort* op      = a.dst[seg] + (size_t)l * a.outL[seg];
    int kb = k_t * 64, nb = n_t * 64;
    int t = threadIdx.x;
    int nl = t & 63, ks = (t >> 6) * 16;
    int n = nb + nl;
    #pragma unroll
    for (int j = 0; j < 16; ++j) {
        float f = (n < N) ? ip[(size_t)(kb + ks + j) * N + n] : 0.f;
        T[nl][ks + j] = f2bf(f);
    }
    __syncthreads();
    int r = t >> 2, c4 = (t & 3) * 16;
    *(short8*)(op + (size_t)(nb + r) * K + kb + c4)     = *(const short8*)&T[r][c4];
    *(short8*)(op + (size_t)(nb + r) * K + kb + c4 + 8) = *(const short8*)&T[r][c4 + 8];
}

// ---------------- GEMM: C[M,N] = A_bf16[M,K] @ Bt_bf16[N,K]^T (+epilogue) --
// EPI 0: bf16 out          EPI 1: fp32 out = acc + bias[col] + res
// EPI 2: bf16 gelu(acc+b)  EPI 3: fp32 out = acc, col<N guarded; z-split via
//                                 blockIdx.z (kOff = z*kLen, out += z*M*ldOut)
// EPI 4: QKV mode: cols<1536 bf16 out; cols>=1536 write V^T to vt[d][m]
// DB: 2-phase double-buffered staging; SWZ: bijective XCD block remap (m204)
template <int BM, int BN, int EPI, bool DB, bool SWZ, int MINW>
__global__ __launch_bounds__(256, MINW) void gemmT(const ushort* __restrict__ A,
                                                   const ushort* __restrict__ Bt,
                                                   const float* __restrict__ bias,
                                                   const float* __restrict__ res,
                                                   void* __restrict__ outp,
                                                   ushort* __restrict__ vt,
                                                   int M, int N, int K,
                                                   int kLen, int ldOut) {
    constexpr int FM = BM / 32;
    constexpr int FN = BN / 32;
    constexpr int NBUF = DB ? 2 : 1;
    constexpr int ASZ = BM * 64;
    constexpr int BSZ = BN * 64;
    __shared__ ushort As[NBUF * ASZ];
    __shared__ ushort Bs[NBUF * BSZ];
    int tid = threadIdx.x, lane = tid & 63, wave = tid >> 6;
    int wm = (wave >> 1) * (BM / 2), wn = (wave & 1) * (BN / 2);
    int mBase, nBase;
    if constexpr (SWZ) {
        int gx = gridDim.x;
        int nwg = gx * gridDim.y;
        int flat = blockIdx.y * gx + blockIdx.x;
        int xcd = flat & 7, idx = flat >> 3;
        int q = nwg >> 3, r = nwg & 7;
        int wg = (xcd < r ? xcd * (q + 1) : r * (q + 1) + (xcd - r) * q) + idx;
        mBase = (wg % gx) * BM;
        nBase = (wg / gx) * BN;
    } else {
        mBase = blockIdx.x * BM;
        nBase = blockIdx.y * BN;
    }
    int kOff = kLen * blockIdx.z;
    int lr = lane & 15, lg = lane >> 4;
    int swz = (lr & 7) << 3;   // element-offset XOR for swizzled reads

    f4v acc[FM][FN];
    #pragma unroll
    for (int i = 0; i < FM; ++i)
        #pragma unroll
        for (int j = 0; j < FN; ++j) acc[i][j] = (f4v){0.f, 0.f, 0.f, 0.f};

    int cBase = wave * 64 + lane;

    auto stage = [&](int kb, int buf) {
        #pragma unroll
        for (int i = 0; i < BM / 32; ++i) {
            int c = i * 256 + cBase;
            int row = c >> 3;
            int kc = (c & 7) ^ (row & 7);     // inverse-swizzled source
            gld16(A + (size_t)(mBase + row) * K + kOff + kb + kc * 8,
                  As + buf * ASZ + (size_t)(i * 256 + wave * 64) * 8);
        }
        #pragma unroll
        for (int i = 0; i < BN / 32; ++i) {
            int c = i * 256 + cBase;
            int row = c >> 3;
            int kc = (c & 7) ^ (row & 7);
            gld16(Bt + (size_t)(nBase + row) * K + kOff + kb + kc * 8,
                  Bs + buf * BSZ + (size_t)(i * 256 + wave * 64) * 8);
        }
    };
    auto compute = [&](int buf) {
        #pragma unroll
        for (int kk = 0; kk < 2; ++kk) {
            short8 a[FM], b[FN];
            #pragma unroll
            for (int fr = 0; fr < FM; ++fr)
                a[fr] = *(const short8*)(As + buf * ASZ + (wm + fr * 16 + lr) * 64 + ((((kk * 4 + lg) << 3)) ^ swz));
            #pragma unroll
            for (int fc = 0; fc < FN; ++fc)
                b[fc] = *(const short8*)(Bs + buf * BSZ + (wn + fc * 16 + lr) * 64 + ((((kk * 4 + lg) << 3)) ^ swz));
            #pragma unroll
            for (int fr = 0; fr < FM; ++fr)
                #pragma unroll
                for (int fc = 0; fc < FN; ++fc)
                    acc[fr][fc] = __builtin_amdgcn_mfma_f32_16x16x32_bf16(a[fr], b[fc], acc[fr][fc], 0, 0, 0);
        }
    };

    if constexpr (DB) {
        stage(0, 0);
        __syncthreads();
        int cur = 0;
        for (int kb = 0; kb < kLen; kb += 64) {
            if (kb + 64 < kLen) stage(kb + 64, cur ^ 1);   // prefetch next tile
            compute(cur);
            __syncthreads();    // readers of cur done + prefetch drained
            cur ^= 1;
        }
    } else {
        for (int kb = 0; kb < kLen; kb += 64) {
            stage(kb, 0);
            __syncthreads();
            compute(0);
            __syncthreads();
        }
    }

    if constexpr (EPI == 4) {
        if (nBase < 1536) {
            #pragma unroll
            for (int fr = 0; fr < FM; ++fr)
                #pragma unroll
                for (int fc = 0; fc < FN; ++fc)
                    #pragma unroll
                    for (int r = 0; r < 4; ++r) {
                        int row = mBase + wm + fr * 16 + 4 * lg + r;
                        int col = nBase + wn + fc * 16 + lr;
                        ((ushort*)outp)[(size_t)row * ldOut + col] = f2bf(acc[fr][fc][r]);
                    }
        } else {
            // V block: write V^T[d][m], d = col-1536, packed 4 bf16 (m contiguous)
            #pragma unroll
            for (int fr = 0; fr < FM; ++fr)
                #pragma unroll
                for (int fc = 0; fc < FN; ++fc) {
                    short4v pk;
                    #pragma unroll
                    for (int r = 0; r < 4; ++r) pk[r] = (short)f2bf(acc[fr][fc][r]);
                    int d  = nBase - 1536 + wn + fc * 16 + lr;
                    int m0 = mBase + wm + fr * 16 + 4 * lg;
                    *(short4v*)(vt + (size_t)d * SEQ + m0) = pk;
                }
        }
        return;
    }

    float* out3 = (float*)outp;
    if constexpr (EPI == 3) out3 += (size_t)blockIdx.z * M * ldOut;

    #pragma unroll
    for (int fr = 0; fr < FM; ++fr)
        #pragma unroll
        for (int fc = 0; fc < FN; ++fc)
            #pragma unroll
            for (int r = 0; r < 4; ++r) {
                int row = mBase + wm + fr * 16 + 4 * lg + r;
                int col = nBase + wn + fc * 16 + lr;
                float v = acc[fr][fc][r];
                if constexpr (EPI == 0) {
                    ((ushort*)outp)[(size_t)row * ldOut + col] = f2bf(v);
                } else if constexpr (EPI == 1) {
                    v += bias[col] + res[(size_t)row * ldOut + col];
                    ((float*)outp)[(size_t)row * ldOut + col] = v;
                } else if constexpr (EPI == 2) {
                    v += bias[col];
                    v = 0.5f * v * (1.f + erff(v * 0.70710678118f));
                    ((ushort*)outp)[(size_t)row * ldOut + col] = f2bf(v);
                } else {
                    if (col < N) out3[(size_t)row * ldOut + col] = v;
                }
            }
}

// ---------------- Flash attention v7: 2-wave blocks (32 q-rows), DB K/V^T
// staging via global_load_lds, XOR-swizzled LDS, full barriers (replay-safe).
__global__ __launch_bounds__(128) void attn_v7(const ushort* __restrict__ Qg,
                                               const ushort* __restrict__ Kg,
                                               const ushort* __restrict__ Vt,
                                               ushort* __restrict__ Og) {
    __shared__ ushort Ks[2 * 4096];    // 2 x [64 krow][64 d swizzled]
    __shared__ ushort Vs[2 * 4096];    // 2 x [64 d][64 m swizzled]
    __shared__ ushort Ps[2 * 1024];    // per-wave [16 qrow][64 k swizzled]
    int tid = threadIdx.x, lane = tid & 63, wave = tid >> 6;
    int flat = blockIdx.x;
    int qt   = (SEQ / 32) - 1 - (flat / NH);   // longest q-tiles first
    int head = flat % NH;
    int lr = lane & 15, lg = lane >> 4;
    int qr0 = qt * 32 + wave * 16;
    int hoff = head * HDM;
    int swz = (lr & 7) << 3;
    int ktiles = (qt * 32 + 31) / 64 + 1;

    short8 qf0 = *(const short8*)(Qg + (size_t)(qr0 + lr) * 2304 + hoff + lg * 8);
    short8 qf1 = *(const short8*)(Qg + (size_t)(qr0 + lr) * 2304 + hoff + 32 + lg * 8);

    const f4v fz = {0.f, 0.f, 0.f, 0.f};
    f4v o[4];
    o[0] = fz; o[1] = fz; o[2] = fz; o[3] = fz;
    float mrow[4] = {-1e30f, -1e30f, -1e30f, -1e30f};
    float lsum[4] = {0.f, 0.f, 0.f, 0.f};

    auto stageKV = [&](int kb, int buf) {
        #pragma unroll
        for (int j = 0; j < 4; ++j) {
            int cc = j * 128 + wave * 64 + lane;
            int row = cc >> 3;
            int kc = (cc & 7) ^ (row & 7);
            gld16(Kg + (size_t)(kb * 64 + row) * 2304 + hoff + kc * 8,
                  Ks + buf * 4096 + (size_t)(j * 128 + wave * 64) * 8);
            gld16(Vt + (size_t)(hoff + row) * SEQ + kb * 64 + kc * 8,
                  Vs + buf * 4096 + (size_t)(j * 128 + wave * 64) * 8);
        }
    };

    stageKV(0, 0);
    __syncthreads();
    int cur = 0;

    for (int kb = 0; kb < ktiles; ++kb) {
        if (kb + 1 < ktiles) stageKV(kb + 1, cur ^ 1);   // prefetch next K/V tile

        // S = Q K^T
        f4v s[4];
        #pragma unroll
        for (int n = 0; n < 4; ++n) {
            const ushort* kr = Ks + cur * 4096 + (n * 16 + lr) * 64;
            short8 k0 = *(const short8*)(kr + ((lg << 3) ^ swz));
            short8 k1 = *(const short8*)(kr + ((((4 + lg) << 3)) ^ swz));
            f4v z = fz;
            z = __builtin_amdgcn_mfma_f32_16x16x32_bf16(qf0, k0, z, 0, 0, 0);
            s[n] = __builtin_amdgcn_mfma_f32_16x16x32_bf16(qf1, k1, z, 0, 0, 0);
        }
        if (kb == ktiles - 1) {
            #pragma unroll
            for (int n = 0; n < 4; ++n)
                #pragma unroll
                for (int r = 0; r < 4; ++r) {
                    int col = kb * 64 + n * 16 + lr;
                    int row = qr0 + 4 * lg + r;
                    if (col > row) s[n][r] = -1e38f;
                }
        }

        // online softmax; P -> per-wave swizzled LDS
        int sub = lr & 7, hi = lr >> 3;
        #pragma unroll
        for (int r = 0; r < 4; ++r) {
            float mx = fmaxf(fmaxf(s[0][r], s[1][r]), fmaxf(s[2][r], s[3][r]));
            mx = fmaxf(mx, __shfl_xor(mx, 1));
            mx = fmaxf(mx, __shfl_xor(mx, 2));
            mx = fmaxf(mx, __shfl_xor(mx, 4));
            mx = fmaxf(mx, __shfl_xor(mx, 8));
            float mnew = fmaxf(mrow[r], mx);
            float corr = __expf(mrow[r] - mnew);
            float ps0 = __expf(s[0][r] - mnew);
            float ps1 = __expf(s[1][r] - mnew);
            float ps2 = __expf(s[2][r] - mnew);
            float ps3 = __expf(s[3][r] - mnew);
            float rs = ps0 + ps1 + ps2 + ps3;
            rs += __shfl_xor(rs, 1);
            rs += __shfl_xor(rs, 2);
            rs += __shfl_xor(rs, 4);
            rs += __shfl_xor(rs, 8);
            lsum[r] = lsum[r] * corr + rs;
            mrow[r] = mnew;
            o[0][r] *= corr; o[1][r] *= corr; o[2][r] *= corr; o[3][r] *= corr;
            int prow = 4 * lg + r;
            ushort* pb = Ps + wave * 1024 + prow * 64;
            int px = prow & 7;
            pb[(((0 + hi) ^ px) << 3) | sub] = f2bf(ps0);
            pb[(((2 + hi) ^ px) << 3) | sub] = f2bf(ps1);
            pb[(((4 + hi) ^ px) << 3) | sub] = f2bf(ps2);
            pb[(((6 + hi) ^ px) << 3) | sub] = f2bf(ps3);
        }
        __syncthreads();   // P ready (also drains prefetch vmcnt)

        // O += P V
        #pragma unroll
        for (int kk = 0; kk < 2; ++kk) {
            short8 pa = *(const short8*)(Ps + wave * 1024 + lr * 64 + ((((kk * 4 + lg) << 3)) ^ swz));
            #pragma unroll
            for (int dn = 0; dn < 4; ++dn) {
                short8 vb = *(const short8*)(Vs + cur * 4096 + (dn * 16 + lr) * 64 + ((((kk * 4 + lg) << 3)) ^ swz));
                o[dn] = __builtin_amdgcn_mfma_f32_16x16x32_bf16(pa, vb, o[dn], 0, 0, 0);
            }
        }
        __syncthreads();   // readers of cur/Ps done before overwrite
        cur ^= 1;
    }

    #pragma unroll
    for (int dn = 0; dn < 4; ++dn)
        #pragma unroll
        for (int r = 0; r < 4; ++r) {
            int row = qr0 + 4 * lg + r;
            Og[(size_t)row * DM + hoff + dn * 16 + lr] = f2bf(o[dn][r] / lsum[r]);
        }
}

// ---------------- fallback-path kernels (round-1 style) --------------------
template <int EPI>
__global__ __launch_bounds__(256) void gemm64(const ushort* __restrict__ A,
                                              const float* __restrict__ B,
                                              const float* __restrict__ bias,
                                              const float* __restrict__ res,
                                              void* __restrict__ outp,
                                              int M, int N, int K) {
    __shared__ ushort As[64][64];
    __shared__ ushort Bs[64][72];
    int tid = threadIdx.x;
    int lane = tid & 63, wave = tid >> 6;
    int wm = (wave >> 1) * 32, wn = (wave & 1) * 32;
    int mBase = blockIdx.x * 64, nBase = blockIdx.y * 64;
    int lr = lane & 15, lg = lane >> 4;

    const f4v fz = {0.f, 0.f, 0.f, 0.f};
    f4v acc[2][2];
    acc[0][0] = fz; acc[0][1] = fz; acc[1][0] = fz; acc[1][1] = fz;

    int ar = tid >> 2, ac = (tid & 3) * 16;
    int br = tid >> 2, bc = (tid & 3) * 16;

    for (int kb = 0; kb < K; kb += 64) {
        const short8* ag = (const short8*)(A + (size_t)(mBase + ar) * K + kb + ac);
        *(short8*)&As[ar][ac]     = ag[0];
        *(short8*)&As[ar][ac + 8] = ag[1];
        if constexpr (EPI == 3) {
            #pragma unroll
            for (int j = 0; j < 16; ++j) {
                int col = nBase + bc + j;
                float f = (col < N) ? B[(size_t)(kb + br) * N + col] : 0.f;
                Bs[bc + j][br] = f2bf(f);
            }
        } else {
            const float4* bg = (const float4*)(B + (size_t)(kb + br) * N + nBase + bc);
            float fv[16];
            *(float4*)&fv[0]  = bg[0];
            *(float4*)&fv[4]  = bg[1];
            *(float4*)&fv[8]  = bg[2];
            *(float4*)&fv[12] = bg[3];
            #pragma unroll
            for (int j = 0; j < 16; ++j) Bs[bc + j][br] = f2bf(fv[j]);
        }
        __syncthreads();
        #pragma unroll
        for (int kk = 0; kk < 2; ++kk) {
            short8 a0 = *(const short8*)&As[wm + lr][kk * 32 + lg * 8];
            short8 a1 = *(const short8*)&As[wm + 16 + lr][kk * 32 + lg * 8];
            short8 b0 = *(const short8*)&Bs[wn + lr][kk * 32 + lg * 8];
            short8 b1 = *(const short8*)&Bs[wn + 16 + lr][kk * 32 + lg * 8];
            acc[0][0] = __builtin_amdgcn_mfma_f32_16x16x32_bf16(a0, b0, acc[0][0], 0, 0, 0);
            acc[0][1] = __builtin_amdgcn_mfma_f32_16x16x32_bf16(a0, b1, acc[0][1], 0, 0, 0);
            acc[1][0] = __builtin_amdgcn_mfma_f32_16x16x32_bf16(a1, b0, acc[1][0], 0, 0, 0);
            acc[1][1] = __builtin_amdgcn_mfma_f32_16x16x32_bf16(a1, b1, acc[1][1], 0, 0, 0);
        }
        __syncthreads();
    }

    #pragma unroll
    for (int fm = 0; fm < 2; ++fm)
        #pragma unroll
        for (int fn = 0; fn < 2; ++fn)
            #pragma unroll
            for (int r = 0; r < 4; ++r) {
                int row = mBase + wm + fm * 16 + 4 * lg + r;
                int col = nBase + wn + fn * 16 + lr;
                float v = acc[fm][fn][r];
                if constexpr (EPI == 0) {
                    ((ushort*)outp)[(size_t)row * N + col] = f2bf(v);
                } else if constexpr (EPI == 1) {
                    v += bias[col] + res[(size_t)row * N + col];
                    ((float*)outp)[(size_t)row * N + col] = v;
                } else if constexpr (EPI == 2) {
                    v += bias[col];
                    v = 0.5f * v * (1.f + erff(v * 0.70710678118f));
                    ((ushort*)outp)[(size_t)row * N + col] = f2bf(v);
                } else {
                    if (col < N) ((float*)outp)[(size_t)row * N + col] = v;
                }
            }
}

__global__ __launch_bounds__(256) void attn_stage(const ushort* __restrict__ Qg,
                                                  const ushort* __restrict__ Kg,
                                                  const ushort* __restrict__ Vg,
                                                  ushort* __restrict__ Og,
                                                  int ld) {
    __shared__ ushort Ks[64][64];
    __shared__ ushort Vs[64][72];
    __shared__ ushort Ps[4][16][64];
    int tid = threadIdx.x, lane = tid & 63, wave = tid >> 6;
    int qb = blockIdx.x, head = blockIdx.y;
    int lr = lane & 15, lg = lane >> 4;
    int qr0 = qb * 64 + wave * 16;
    size_t hoff = (size_t)head * HDM;

    short8 qf0 = *(const short8*)(Qg + (size_t)(qr0 + lr) * ld + hoff + lg * 8);
    short8 qf1 = *(const short8*)(Qg + (size_t)(qr0 + lr) * ld + hoff + 32 + lg * 8);

    const f4v fz = {0.f, 0.f, 0.f, 0.f};
    f4v o[4];
    o[0] = fz; o[1] = fz; o[2] = fz; o[3] = fz;
    float mrow[4] = {-1e30f, -1e30f, -1e30f, -1e30f};
    float lsum[4] = {0.f, 0.f, 0.f, 0.f};

    int r_ = tid >> 2, c_ = (tid & 3) * 16;

    for (int kb = 0; kb <= qb; ++kb) {
        const short8* kg = (const short8*)(Kg + (size_t)(kb * 64 + r_) * ld + hoff + c_);
        *(short8*)&Ks[r_][c_]     = kg[0];
        *(short8*)&Ks[r_][c_ + 8] = kg[1];
        const short8* vg = (const short8*)(Vg + (size_t)(kb * 64 + r_) * ld + hoff + c_);
        short8 v0 = vg[0], v1 = vg[1];
        #pragma unroll
        for (int j = 0; j < 8; ++j) {
            Vs[c_ + j][r_]     = (ushort)v0[j];
            Vs[c_ + 8 + j][r_] = (ushort)v1[j];
        }
        __syncthreads();

        f4v s[4];
        #pragma unroll
        for (int n = 0; n < 4; ++n) {
            short8 k0 = *(const short8*)&Ks[n * 16 + lr][lg * 8];
            short8 k1 = *(const short8*)&Ks[n * 16 + lr][32 + lg * 8];
            f4v z = fz;
            z = __builtin_amdgcn_mfma_f32_16x16x32_bf16(qf0, k0, z, 0, 0, 0);
            s[n] = __builtin_amdgcn_mfma_f32_16x16x32_bf16(qf1, k1, z, 0, 0, 0);
        }
        if (kb == qb) {
            #pragma unroll
            for (int n = 0; n < 4; ++n)
                #pragma unroll
                for (int r = 0; r < 4; ++r) {
                    int col = kb * 64 + n * 16 + lr;
                    int row = qr0 + 4 * lg + r;
                    if (col > row) s[n][r] = -1e38f;
                }
        }

        #pragma unroll
        for (int r = 0; r < 4; ++r) {
            float mx = fmaxf(fmaxf(s[0][r], s[1][r]), fmaxf(s[2][r], s[3][r]));
            mx = fmaxf(mx, __shfl_xor(mx, 1));
            mx = fmaxf(mx, __shfl_xor(mx, 2));
            mx = fmaxf(mx, __shfl_xor(mx, 4));
            mx = fmaxf(mx, __shfl_xor(mx, 8));
            float mnew = fmaxf(mrow[r], mx);
            float corr = __expf(mrow[r] - mnew);
            float ps0 = __expf(s[0][r] - mnew);
            float ps1 = __expf(s[1][r] - mnew);
            float ps2 = __expf(s[2][r] - mnew);
            float ps3 = __expf(s[3][r] - mnew);
            float rs = ps0 + ps1 + ps2 + ps3;
            rs += __shfl_xor(rs, 1);
            rs += __shfl_xor(rs, 2);
            rs += __shfl_xor(rs, 4);
            rs += __shfl_xor(rs, 8);
            lsum[r] = lsum[r] * corr + rs;
            mrow[r] = mnew;
            o[0][r] *= corr; o[1][r] *= corr; o[2][r] *= corr; o[3][r] *= corr;
            Ps[wave][4 * lg + r][0 * 16 + lr] = f2bf(ps0);
            Ps[wave][4 * lg + r][1 * 16 + lr] = f2bf(ps1);
            Ps[wave][4 * lg + r][2 * 16 + lr] = f2bf(ps2);
            Ps[wave][4 * lg + r][3 * 16 + lr] = f2bf(ps3);
        }
        __syncthreads();

        #pragma unroll
        for (int kk = 0; kk < 2; ++kk) {
            short8 pa = *(const short8*)&Ps[wave][lr][kk * 32 + lg * 8];
            #pragma unroll
            for (int dn = 0; dn < 4; ++dn) {
                short8 vb = *(const short8*)&Vs[dn * 16 + lr][kk * 32 + lg * 8];
                o[dn] = __builtin_amdgcn_mfma_f32_16x16x32_bf16(pa, vb, o[dn], 0, 0, 0);
            }
        }
        __syncthreads();
    }

    #pragma unroll
    for (int dn = 0; dn < 4; ++dn)
        #pragma unroll
        for (int r = 0; r < 4; ++r) {
            int row = qr0 + 4 * lg + r;
            Og[(size_t)row * DM + hoff + dn * 16 + lr] = f2bf(o[dn][r] / lsum[r]);
        }
}

extern "C" void kernel_launch(void* const* d_in, const int* in_sizes, int n_in,
                              void* d_out, int out_size, void* d_ws, size_t ws_size,
                              hipStream_t stream) {
    const float* x     = (const float*)d_in[0];
    const float* ln1_g = (const float*)d_in[1];
    const float* ln1_b = (const float*)d_in[2];
    const float* Wq    = (const float*)d_in[3];
    const float* Wk    = (const float*)d_in[4];
    const float* Wv    = (const float*)d_in[5];
    const float* Wo    = (const float*)d_in[6];
    const float* bo    = (const float*)d_in[7];
    const float* ln2_g = (const float*)d_in[8];
    const float* ln2_b = (const float*)d_in[9];
    const float* Wfc   = (const float*)d_in[10];
    const float* bfc   = (const float*)d_in[11];
    const float* Wp    = (const float*)d_in[12];
    const float* bp    = (const float*)d_in[13];
    const float* lnf_g = (const float*)d_in[14];
    const float* lnf_b = (const float*)d_in[15];
    const float* Wlm   = (const float*)d_in[16];

    dim3 blk(256);

    // ---- workspace layout (new path) ----
    size_t offs[13];
    size_t need = 0;
    size_t sizes[12] = {
        (size_t)SEQ * DM * 4,          // h (fp32)
        (size_t)SEQ * DM * 2,          // hn
        (size_t)SEQ * 2304 * 2,        // qkv packed
        (size_t)SEQ * DM * 2,          // ab
        (size_t)SEQ * FF * 2,          // fb
        (size_t)DM * SEQ * 2,          // vT [768][2048]
        (size_t)NL * 2304 * DM * 2,    // qkvw^T packed
        (size_t)NL * DM * DM * 2,      // Wo^T
        (size_t)NL * FF * DM * 2,      // Wfc^T
        (size_t)NL * DM * FF * 2,      // Wp^T
        (size_t)NVP * DM * 2,          // Wlm^T [50496][768]
        (size_t)4 * SEQ * DM * 4,      // spk: split-K partials (25 MB)
    };
    for (int i = 0; i < 12; ++i) { offs[i] = need; need += sizes[i]; }
    offs[12] = need;
    size_t need_base = offs[11];       // without spk
    bool useSpk = (ws_size >= need);

    if (ws_size >= need_base) {
        char* ws = (char*)d_ws;
        float*  h    = (float*)(ws + offs[0]);
        ushort* hn   = (ushort*)(ws + offs[1]);
        ushort* qkv  = (ushort*)(ws + offs[2]);
        ushort* ab_  = (ushort*)(ws + offs[3]);
        ushort* fb_  = (ushort*)(ws + offs[4]);
        ushort* vt   = (ushort*)(ws + offs[5]);
        ushort* qkvw = (ushort*)(ws + offs[6]);
        ushort* wow  = (ushort*)(ws + offs[7]);
        ushort* fcw  = (ushort*)(ws + offs[8]);
        ushort* wpw  = (ushort*)(ws + offs[9]);
        ushort* lmw  = (ushort*)(ws + offs[10]);
        float*  spk  = (float*)(ws + offs[11]);

        hipMemcpyAsync(h, x, (size_t)SEQ * DM * 4, hipMemcpyDeviceToDevice, stream);

        // ---- single merged weight-conversion dispatch ----
        CvtArgs ca;
        const float* srcs[7] = {Wq, Wk, Wv, Wo, Wfc, Wp, Wlm};
        ushort* dsts[7] = {qkvw, qkvw + DM * DM, qkvw + 2 * DM * DM, wow, fcw, wpw, lmw};
        long inLs[7]  = {(long)DM * DM, (long)DM * DM, (long)DM * DM, (long)DM * DM,
                         (long)DM * FF, (long)FF * DM, 0};
        long outLs[7] = {(long)2304 * DM, (long)2304 * DM, (long)2304 * DM, (long)DM * DM,
                         (long)FF * DM, (long)DM * FF, 0};
        int Ks_[7] = {DM, DM, DM, DM, DM, FF, DM};
        int Ns_[7] = {DM, DM, DM, DM, FF, DM, NV};
        int tks[7] = {12, 12, 12, 12, 12, 48, 12};
        int tns[7] = {12, 12, 12, 12, 48, 12, NVP / 64};
        int lays[7] = {NL, NL, NL, NL, NL, NL, 1};
        int total = 0;
        for (int i = 0; i < 7; ++i) {
            ca.src[i] = srcs[i]; ca.dst[i] = dsts[i];
            ca.inL[i] = inLs[i]; ca.outL[i] = outLs[i];
            ca.K[i] = Ks_[i]; ca.N[i] = Ns_[i]; ca.tk[i] = tks[i]; ca.tn[i] = tns[i];
            ca.base[i] = total;
            total += tks[i] * tns[i] * lays[i];
        }
        ca.base[7] = total;
        cvt_all<<<dim3(total), blk, 0, stream>>>(ca);

        ln_kernel<<<SEQ, blk, 0, stream>>>(h, ln1_g, ln1_b, hn);
        for (int l = 0; l < NL; ++l) {
            const ushort* qw = qkvw + (size_t)l * 2304 * DM;
            gemmT<64, 64, 4, true, false, 2><<<dim3(32, 36), blk, 0, stream>>>(hn, qw, nullptr, nullptr, qkv, vt, SEQ, 2304, DM, DM, 2304);
            attn_v7<<<dim3((SEQ / 32) * NH), dim3(128), 0, stream>>>(qkv, qkv + 768, vt, ab_);
            if (useSpk) {
                gemmT<64, 64, 3, true, false, 2><<<dim3(32, 12, 2), blk, 0, stream>>>(ab_, wow + (size_t)l * DM * DM, nullptr, nullptr, spk, nullptr, SEQ, DM, DM, DM / 2, DM);
                ln_spk<2><<<SEQ, blk, 0, stream>>>(spk, bo + l * DM, h, ln2_g + l * DM, ln2_b + l * DM, hn);
            } else {
                gemmT<64, 64, 1, true, false, 2><<<dim3(32, 12), blk, 0, stream>>>(ab_, wow + (size_t)l * DM * DM, bo + l * DM, h, h, nullptr, SEQ, DM, DM, DM, DM);
                ln_kernel<<<SEQ, blk, 0, stream>>>(h, ln2_g + l * DM, ln2_b + l * DM, hn);
            }
            gemmT<64, 64, 2, true, false, 2><<<dim3(32, 48), blk, 0, stream>>>(hn, fcw + (size_t)l * FF * DM, bfc + l * FF, nullptr, fb_, nullptr, SEQ, FF, DM, DM, FF);
            const float* g2 = (l + 1 < NL) ? ln1_g + (l + 1) * DM : lnf_g;
            const float* b2 = (l + 1 < NL) ? ln1_b + (l + 1) * DM : lnf_b;
            if (useSpk) {
                gemmT<64, 64, 3, true, false, 2><<<dim3(32, 12, 4), blk, 0, stream>>>(fb_, wpw + (size_t)l * DM * FF, nullptr, nullptr, spk, nullptr, SEQ, DM, FF, FF / 4, DM);
                ln_spk<4><<<SEQ, blk, 0, stream>>>(spk, bp + l * DM, h, g2, b2, hn);
            } else {
                gemmT<64, 64, 1, true, false, 2><<<dim3(32, 12), blk, 0, stream>>>(fb_, wpw + (size_t)l * DM * FF, bp + l * DM, h, h, nullptr, SEQ, DM, FF, FF, DM);
                ln_kernel<<<SEQ, blk, 0, stream>>>(h, g2, b2, hn);
            }
        }
        gemmT<128, 192, 3, false, true, 3><<<dim3(16, NVP / 192), blk, 0, stream>>>(hn, lmw, nullptr, nullptr, d_out, nullptr, SEQ, NV, DM, DM, NV);
        return;
    }

    // ---------------- fallback: round-1 path (fp32-B GEMMs) ----------------
    char* ws = (char*)d_ws;
    float*  h   = (float*)ws;   ws += (size_t)SEQ * DM * 4;
    ushort* hn  = (ushort*)ws;  ws += (size_t)SEQ * DM * 2;
    ushort* qb_ = (ushort*)ws;  ws += (size_t)SEQ * DM * 2;
    ushort* kb_ = (ushort*)ws;  ws += (size_t)SEQ * DM * 2;
    ushort* vb_ = (ushort*)ws;  ws += (size_t)SEQ * DM * 2;
    ushort* ab_ = (ushort*)ws;  ws += (size_t)SEQ * DM * 2;
    ushort* fb_ = (ushort*)ws;  ws += (size_t)SEQ * FF * 2;

    hipMemcpyAsync(h, x, (size_t)SEQ * DM * 4, hipMemcpyDeviceToDevice, stream);

    dim3 gdd(SEQ / 64, DM / 64);
    dim3 gdf(SEQ / 64, FF / 64);
    dim3 gda(SEQ / 64, NH);
    dim3 gdl(SEQ / 64, (NV + 63) / 64);

    for (int l = 0; l < NL; ++l) {
        ln_kernel<<<SEQ, blk, 0, stream>>>(h, ln1_g + l * DM, ln1_b + l * DM, hn);
        gemm64<0><<<gdd, blk, 0, stream>>>(hn, Wq + (size_t)l * DM * DM, nullptr, nullptr, qb_, SEQ, DM, DM);
        gemm64<0><<<gdd, blk, 0, stream>>>(hn, Wk + (size_t)l * DM * DM, nullptr, nullptr, kb_, SEQ, DM, DM);
        gemm64<0><<<gdd, blk, 0, stream>>>(hn, Wv + (size_t)l * DM * DM, nullptr, nullptr, vb_, SEQ, DM, DM);
        attn_stage<<<gda, blk, 0, stream>>>(qb_, kb_, vb_, ab_, DM);
        gemm64<1><<<gdd, blk, 0, stream>>>(ab_, Wo + (size_t)l * DM * DM, bo + l * DM, h, h, SEQ, DM, DM);
        ln_kernel<<<SEQ, blk, 0, stream>>>(h, ln2_g + l * DM, ln2_b + l * DM, hn);
        gemm64<2><<<gdf, blk, 0, stream>>>(hn, Wfc + (size_t)l * DM * FF, bfc + l * FF, nullptr, fb_, SEQ, FF, DM);
        gemm64<1><<<gdd, blk, 0, stream>>>(fb_, Wp + (size_t)l * FF * DM, bp + l * DM, h, h, SEQ, DM, FF);
    }
    ln_kernel<<<SEQ, blk, 0, stream>>>(h, lnf_g, lnf_b, hn);
    gemm64<3><<<gdl, blk, 0, stream>>>(hn, Wlm, nullptr, nullptr, d_out, SEQ, NV, DM);
}

// Round 13
// 2336.628 us; speedup vs baseline: 1.1704x; 1.0088x over previous
//
#include <hip/hip_runtime.h>
#include <hip/hip_bf16.h>
#include <math.h>

typedef unsigned short ushort;
typedef __attribute__((ext_vector_type(8))) short short8;
typedef __attribute__((ext_vector_type(4))) short short4v;
typedef __attribute__((ext_vector_type(4))) float f4v;

constexpr int SEQ = 2048;
constexpr int DM  = 768;
constexpr int NH  = 12;
constexpr int HDM = 64;
constexpr int FF  = 3072;
constexpr int NL  = 12;
constexpr int NV  = 50257;
constexpr int NVP = 50496;   // NV padded to 192

__device__ inline ushort f2bf(float f) {
    union { float f; unsigned u; } v; v.f = f;
    unsigned r = v.u + 0x7fffu + ((v.u >> 16) & 1u);
    return (ushort)(r >> 16);
}

__device__ __forceinline__ void gld16(const ushort* g, ushort* l) {
    __builtin_amdgcn_global_load_lds(
        (const __attribute__((address_space(1))) void*)g,
        (__attribute__((address_space(3))) void*)l, 16, 0, 0);
}

// ---------------- LayerNorm: fp32 in -> bf16 out ----------------
__global__ __launch_bounds__(256) void ln_kernel(const float* __restrict__ x,
                                                 const float* __restrict__ g,
                                                 const float* __restrict__ b,
                                                 ushort* __restrict__ out) {
    int row = blockIdx.x;
    int t = threadIdx.x;
    const float* xr = x + (size_t)row * DM;
    float v0 = xr[t], v1 = xr[t + 256], v2 = xr[t + 512];
    float s = v0 + v1 + v2;
    float s2 = v0 * v0 + v1 * v1 + v2 * v2;
    for (int m = 1; m < 64; m <<= 1) { s += __shfl_xor(s, m); s2 += __shfl_xor(s2, m); }
    __shared__ float ls[4], ls2[4];
    int w = t >> 6;
    if ((t & 63) == 0) { ls[w] = s; ls2[w] = s2; }
    __syncthreads();
    s = ls[0] + ls[1] + ls[2] + ls[3];
    s2 = ls2[0] + ls2[1] + ls2[2] + ls2[3];
    float mu = s * (1.0f / DM);
    float var = s2 * (1.0f / DM) - mu * mu;
    float rs = rsqrtf(var + 1e-5f);
    ushort* o = out + (size_t)row * DM;
    o[t]       = f2bf((v0 - mu) * rs * g[t]       + b[t]);
    o[t + 256] = f2bf((v1 - mu) * rs * g[t + 256] + b[t + 256]);
    o[t + 512] = f2bf((v2 - mu) * rs * g[t + 512] + b[t + 512]);
}

// ------- fused: h += bias + sum(NS split-K partials); hn = LN(h)*g+b --------
template <int NS>
__global__ __launch_bounds__(256) void ln_spk(const float* __restrict__ p,
                                              const float* __restrict__ bias,
                                              float* __restrict__ h,
                                              const float* __restrict__ g,
                                              const float* __restrict__ b,
                                              ushort* __restrict__ out) {
    int row = blockIdx.x;
    int t = threadIdx.x;
    size_t base = (size_t)row * DM;
    float v[3];
    #pragma unroll
    for (int j = 0; j < 3; ++j) {
        int col = t + j * 256;
        float acc = h[base + col] + bias[col];
        #pragma unroll
        for (int s = 0; s < NS; ++s) acc += p[(size_t)s * SEQ * DM + base + col];
        v[j] = acc;
        h[base + col] = acc;
    }
    float s1 = v[0] + v[1] + v[2];
    float s2 = v[0] * v[0] + v[1] * v[1] + v[2] * v[2];
    for (int m = 1; m < 64; m <<= 1) { s1 += __shfl_xor(s1, m); s2 += __shfl_xor(s2, m); }
    __shared__ float ls[4], ls2[4];
    int w = t >> 6;
    if ((t & 63) == 0) { ls[w] = s1; ls2[w] = s2; }
    __syncthreads();
    s1 = ls[0] + ls[1] + ls[2] + ls[3];
    s2 = ls2[0] + ls2[1] + ls2[2] + ls2[3];
    float mu = s1 * (1.0f / DM);
    float var = s2 * (1.0f / DM) - mu * mu;
    float rs = rsqrtf(var + 1e-5f);
    #pragma unroll
    for (int j = 0; j < 3; ++j) {
        int col = t + j * 256;
        out[base + col] = f2bf((v[j] - mu) * rs * g[col] + b[col]);
    }
}

// ---------------- merged transpose-convert: fp32 [K][N] -> bf16 [N][K] -----
struct CvtArgs {
    const float* src[7];
    ushort*      dst[7];
    long inL[7], outL[7];
    int  K[7], N[7], tk[7], tn[7];
    int  base[8];
};

__global__ __launch_bounds__(256) void cvt_all(CvtArgs a) {
    __shared__ ushort T[64][72];
    int idx = blockIdx.x;
    int seg = 0;
    #pragma unroll
    for (int i = 1; i < 7; ++i) if (idx >= a.base[i]) seg = i;
    int local = idx - a.base[seg];
    int K = a.K[seg], N = a.N[seg];
    int tk = a.tk[seg], tn = a.tn[seg];
    int k_t = local % tk;
    int rst = local / tk;
    int n_t = rst % tn;
    int l   = rst / tn;
    const float* ip = a.src[seg] + (size_t)l * a.inL[seg];
    ushort* op      = a.dst[seg] + (size_t)l * a.outL[seg];
    int kb = k_t * 64, nb = n_t * 64;
    int t = threadIdx.x;
    int nl = t & 63, ks = (t >> 6) * 16;
    int n = nb + nl;
    #pragma unroll
    for (int j = 0; j < 16; ++j) {
        float f = (n < N) ? ip[(size_t)(kb + ks + j) * N + n] : 0.f;
        T[nl][ks + j] = f2bf(f);
    }
    __syncthreads();
    int r = t >> 2, c4 = (t & 3) * 16;
    *(short8*)(op + (size_t)(nb + r) * K + kb + c4)     = *(const short8*)&T[r][c4];
    *(short8*)(op + (size_t)(nb + r) * K + kb + c4 + 8) = *(const short8*)&T[r][c4 + 8];
}

// ---------------- GEMM: C[M,N] = A_bf16[M,K] @ Bt_bf16[N,K]^T (+epilogue) --
// EPI 0: bf16 out          EPI 1: fp32 out = acc + bias[col] + res
// EPI 2: bf16 gelu(acc+b)  EPI 3: fp32 out = acc, col<N guarded; z-split via
//                                 blockIdx.z (kOff = z*kLen, out += z*M*ldOut)
// EPI 4: QKV mode: cols<1536 bf16 out; cols>=1536 write V^T to vt[d][m]
// DB: 2-phase double-buffered staging; SWZ: bijective XCD block remap (m204)
template <int BM, int BN, int EPI, bool DB, bool SWZ, int MINW>
__global__ __launch_bounds__(256, MINW) void gemmT(const ushort* __restrict__ A,
                                                   const ushort* __restrict__ Bt,
                                                   const float* __restrict__ bias,
                                                   const float* __restrict__ res,
                                                   void* __restrict__ outp,
                                                   ushort* __restrict__ vt,
                                                   int M, int N, int K,
                                                   int kLen, int ldOut) {
    constexpr int FM = BM / 32;
    constexpr int FN = BN / 32;
    constexpr int NBUF = DB ? 2 : 1;
    constexpr int ASZ = BM * 64;
    constexpr int BSZ = BN * 64;
    __shared__ ushort As[NBUF * ASZ];
    __shared__ ushort Bs[NBUF * BSZ];
    int tid = threadIdx.x, lane = tid & 63, wave = tid >> 6;
    int wm = (wave >> 1) * (BM / 2), wn = (wave & 1) * (BN / 2);
    int mBase, nBase;
    if constexpr (SWZ) {
        int gx = gridDim.x;
        int nwg = gx * gridDim.y;
        int flat = blockIdx.y * gx + blockIdx.x;
        int xcd = flat & 7, idx = flat >> 3;
        int q = nwg >> 3, r = nwg & 7;
        int wg = (xcd < r ? xcd * (q + 1) : r * (q + 1) + (xcd - r) * q) + idx;
        mBase = (wg % gx) * BM;
        nBase = (wg / gx) * BN;
    } else {
        mBase = blockIdx.x * BM;
        nBase = blockIdx.y * BN;
    }
    int kOff = kLen * blockIdx.z;
    int lr = lane & 15, lg = lane >> 4;
    int swz = (lr & 7) << 3;   // element-offset XOR for swizzled reads

    f4v acc[FM][FN];
    #pragma unroll
    for (int i = 0; i < FM; ++i)
        #pragma unroll
        for (int j = 0; j < FN; ++j) acc[i][j] = (f4v){0.f, 0.f, 0.f, 0.f};

    int cBase = wave * 64 + lane;

    auto stage = [&](int kb, int buf) {
        #pragma unroll
        for (int i = 0; i < BM / 32; ++i) {
            int c = i * 256 + cBase;
            int row = c >> 3;
            int kc = (c & 7) ^ (row & 7);     // inverse-swizzled source
            gld16(A + (size_t)(mBase + row) * K + kOff + kb + kc * 8,
                  As + buf * ASZ + (size_t)(i * 256 + wave * 64) * 8);
        }
        #pragma unroll
        for (int i = 0; i < BN / 32; ++i) {
            int c = i * 256 + cBase;
            int row = c >> 3;
            int kc = (c & 7) ^ (row & 7);
            gld16(Bt + (size_t)(nBase + row) * K + kOff + kb + kc * 8,
                  Bs + buf * BSZ + (size_t)(i * 256 + wave * 64) * 8);
        }
    };
    auto compute = [&](int buf) {
        #pragma unroll
        for (int kk = 0; kk < 2; ++kk) {
            short8 a[FM], b[FN];
            #pragma unroll
            for (int fr = 0; fr < FM; ++fr)
                a[fr] = *(const short8*)(As + buf * ASZ + (wm + fr * 16 + lr) * 64 + ((((kk * 4 + lg) << 3)) ^ swz));
            #pragma unroll
            for (int fc = 0; fc < FN; ++fc)
                b[fc] = *(const short8*)(Bs + buf * BSZ + (wn + fc * 16 + lr) * 64 + ((((kk * 4 + lg) << 3)) ^ swz));
            #pragma unroll
            for (int fr = 0; fr < FM; ++fr)
                #pragma unroll
                for (int fc = 0; fc < FN; ++fc)
                    acc[fr][fc] = __builtin_amdgcn_mfma_f32_16x16x32_bf16(a[fr], b[fc], acc[fr][fc], 0, 0, 0);
        }
    };

    if constexpr (DB) {
        stage(0, 0);
        __syncthreads();
        int cur = 0;
        for (int kb = 0; kb < kLen; kb += 64) {
            if (kb + 64 < kLen) stage(kb + 64, cur ^ 1);   // prefetch next tile
            compute(cur);
            __syncthreads();    // readers of cur done + prefetch drained
            cur ^= 1;
        }
    } else {
        for (int kb = 0; kb < kLen; kb += 64) {
            stage(kb, 0);
            __syncthreads();
            compute(0);
            __syncthreads();
        }
    }

    if constexpr (EPI == 4) {
        if (nBase < 1536) {
            #pragma unroll
            for (int fr = 0; fr < FM; ++fr)
                #pragma unroll
                for (int fc = 0; fc < FN; ++fc)
                    #pragma unroll
                    for (int r = 0; r < 4; ++r) {
                        int row = mBase + wm + fr * 16 + 4 * lg + r;
                        int col = nBase + wn + fc * 16 + lr;
                        ((ushort*)outp)[(size_t)row * ldOut + col] = f2bf(acc[fr][fc][r]);
                    }
        } else {
            // V block: write V^T[d][m], d = col-1536, packed 4 bf16 (m contiguous)
            #pragma unroll
            for (int fr = 0; fr < FM; ++fr)
                #pragma unroll
                for (int fc = 0; fc < FN; ++fc) {
                    short4v pk;
                    #pragma unroll
                    for (int r = 0; r < 4; ++r) pk[r] = (short)f2bf(acc[fr][fc][r]);
                    int d  = nBase - 1536 + wn + fc * 16 + lr;
                    int m0 = mBase + wm + fr * 16 + 4 * lg;
                    *(short4v*)(vt + (size_t)d * SEQ + m0) = pk;
                }
        }
        return;
    }

    float* out3 = (float*)outp;
    if constexpr (EPI == 3) out3 += (size_t)blockIdx.z * M * ldOut;

    #pragma unroll
    for (int fr = 0; fr < FM; ++fr)
        #pragma unroll
        for (int fc = 0; fc < FN; ++fc)
            #pragma unroll
            for (int r = 0; r < 4; ++r) {
                int row = mBase + wm + fr * 16 + 4 * lg + r;
                int col = nBase + wn + fc * 16 + lr;
                float v = acc[fr][fc][r];
                if constexpr (EPI == 0) {
                    ((ushort*)outp)[(size_t)row * ldOut + col] = f2bf(v);
                } else if constexpr (EPI == 1) {
                    v += bias[col] + res[(size_t)row * ldOut + col];
                    ((float*)outp)[(size_t)row * ldOut + col] = v;
                } else if constexpr (EPI == 2) {
                    v += bias[col];
                    v = 0.5f * v * (1.f + erff(v * 0.70710678118f));
                    ((ushort*)outp)[(size_t)row * ldOut + col] = f2bf(v);
                } else {
                    if (col < N) out3[(size_t)row * ldOut + col] = v;
                }
            }
}

// ---------------- Flash attention v9: 2-wave blocks (32 q-rows), 3-buffer K
// staging (ONE barrier per K-tile; 3-buffer makes the single barrier safe),
// V^T read directly from global (L2-resident, identical frags both waves),
// V loads hoisted before the barrier so softmax covers their latency.
// LDS 26 KB -> 6 blocks/CU (12 waves/CU vs v7's 8). Replay-safe: all
// cross-wave ordering on real __syncthreads.
__global__ __launch_bounds__(128) void attn_v9(const ushort* __restrict__ Qg,
                                               const ushort* __restrict__ Kg,
                                               const ushort* __restrict__ Vt,
                                               ushort* __restrict__ Og) {
    __shared__ ushort Ks[3 * 4096];    // 3 x [64 krow][64 d swizzled]
    __shared__ ushort Ps[2 * 1024];    // per-wave [16 qrow][64 k swizzled]
    int tid = threadIdx.x, lane = tid & 63, wave = tid >> 6;
    int flat = blockIdx.x;
    int qt   = (SEQ / 32) - 1 - (flat / NH);   // longest q-tiles first
    int head = flat % NH;
    int lr = lane & 15, lg = lane >> 4;
    int qr0 = qt * 32 + wave * 16;
    int hoff = head * HDM;
    int swz = (lr & 7) << 3;
    int ktiles = (qt * 32 + 31) / 64 + 1;

    short8 qf0 = *(const short8*)(Qg + (size_t)(qr0 + lr) * 2304 + hoff + lg * 8);
    short8 qf1 = *(const short8*)(Qg + (size_t)(qr0 + lr) * 2304 + hoff + 32 + lg * 8);

    const f4v fz = {0.f, 0.f, 0.f, 0.f};
    f4v o[4];
    o[0] = fz; o[1] = fz; o[2] = fz; o[3] = fz;
    float mrow[4] = {-1e30f, -1e30f, -1e30f, -1e30f};
    float lsum[4] = {0.f, 0.f, 0.f, 0.f};

    auto stageK = [&](int kb, int buf) {
        #pragma unroll
        for (int j = 0; j < 4; ++j) {
            int cc = j * 128 + wave * 64 + lane;
            int row = cc >> 3;
            int kc = (cc & 7) ^ (row & 7);
            gld16(Kg + (size_t)(kb * 64 + row) * 2304 + hoff + kc * 8,
                  Ks + buf * 4096 + (size_t)(j * 128 + wave * 64) * 8);
        }
    };

    stageK(0, 0);
    __syncthreads();
    int cur = 0, nxt = 1;

    for (int kb = 0; kb < ktiles; ++kb) {
        if (kb + 1 < ktiles) stageK(kb + 1, nxt);   // prefetch next K tile

        // S = Q K^T (reads Ks[cur], staged by prev iter's prefetch + barrier)
        f4v s[4];
        #pragma unroll
        for (int n = 0; n < 4; ++n) {
            const ushort* kr = Ks + cur * 4096 + (n * 16 + lr) * 64;
            short8 k0 = *(const short8*)(kr + ((lg << 3) ^ swz));
            short8 k1 = *(const short8*)(kr + ((((4 + lg) << 3)) ^ swz));
            f4v z = fz;
            z = __builtin_amdgcn_mfma_f32_16x16x32_bf16(qf0, k0, z, 0, 0, 0);
            s[n] = __builtin_amdgcn_mfma_f32_16x16x32_bf16(qf1, k1, z, 0, 0, 0);
        }

        // hoist V^T global loads: latency hidden under softmax (no LDS dep)
        short8 vb[2][4];
        #pragma unroll
        for (int kk = 0; kk < 2; ++kk)
            #pragma unroll
            for (int dn = 0; dn < 4; ++dn)
                vb[kk][dn] = *(const short8*)(Vt + (size_t)(hoff + dn * 16 + lr) * SEQ + kb * 64 + kk * 32 + lg * 8);

        if (kb == ktiles - 1) {
            #pragma unroll
            for (int n = 0; n < 4; ++n)
                #pragma unroll
                for (int r = 0; r < 4; ++r) {
                    int col = kb * 64 + n * 16 + lr;
                    int row = qr0 + 4 * lg + r;
                    if (col > row) s[n][r] = -1e38f;
                }
        }

        // online softmax; P -> per-wave swizzled LDS
        int sub = lr & 7, hi = lr >> 3;
        #pragma unroll
        for (int r = 0; r < 4; ++r) {
            float mx = fmaxf(fmaxf(s[0][r], s[1][r]), fmaxf(s[2][r], s[3][r]));
            mx = fmaxf(mx, __shfl_xor(mx, 1));
            mx = fmaxf(mx, __shfl_xor(mx, 2));
            mx = fmaxf(mx, __shfl_xor(mx, 4));
            mx = fmaxf(mx, __shfl_xor(mx, 8));
            float mnew = fmaxf(mrow[r], mx);
            float corr = __expf(mrow[r] - mnew);
            float ps0 = __expf(s[0][r] - mnew);
            float ps1 = __expf(s[1][r] - mnew);
            float ps2 = __expf(s[2][r] - mnew);
            float ps3 = __expf(s[3][r] - mnew);
            float rs = ps0 + ps1 + ps2 + ps3;
            rs += __shfl_xor(rs, 1);
            rs += __shfl_xor(rs, 2);
            rs += __shfl_xor(rs, 4);
            rs += __shfl_xor(rs, 8);
            lsum[r] = lsum[r] * corr + rs;
            mrow[r] = mnew;
            o[0][r] *= corr; o[1][r] *= corr; o[2][r] *= corr; o[3][r] *= corr;
            int prow = 4 * lg + r;
            ushort* pb = Ps + wave * 1024 + prow * 64;
            int px = prow & 7;
            pb[(((0 + hi) ^ px) << 3) | sub] = f2bf(ps0);
            pb[(((2 + hi) ^ px) << 3) | sub] = f2bf(ps1);
            pb[(((4 + hi) ^ px) << 3) | sub] = f2bf(ps2);
            pb[(((6 + hi) ^ px) << 3) | sub] = f2bf(ps3);
        }
        __syncthreads();   // P ready + prefetch drained (single barrier/tile)

        // O += P V
        #pragma unroll
        for (int kk = 0; kk < 2; ++kk) {
            short8 pa = *(const short8*)(Ps + wave * 1024 + lr * 64 + ((((kk * 4 + lg) << 3)) ^ swz));
            #pragma unroll
            for (int dn = 0; dn < 4; ++dn)
                o[dn] = __builtin_amdgcn_mfma_f32_16x16x32_bf16(pa, vb[kk][dn], o[dn], 0, 0, 0);
        }
        // no second barrier: 3-buffer rotation protects Ks; Ps is per-wave
        cur = nxt;
        nxt = nxt + 1 == 3 ? 0 : nxt + 1;
    }

    #pragma unroll
    for (int dn = 0; dn < 4; ++dn)
        #pragma unroll
        for (int r = 0; r < 4; ++r) {
            int row = qr0 + 4 * lg + r;
            Og[(size_t)row * DM + hoff + dn * 16 + lr] = f2bf(o[dn][r] / lsum[r]);
        }
}

// ---------------- fallback-path kernels (round-1 style) --------------------
template <int EPI>
__global__ __launch_bounds__(256) void gemm64(const ushort* __restrict__ A,
                                              const float* __restrict__ B,
                                              const float* __restrict__ bias,
                                              const float* __restrict__ res,
                                              void* __restrict__ outp,
                                              int M, int N, int K) {
    __shared__ ushort As[64][64];
    __shared__ ushort Bs[64][72];
    int tid = threadIdx.x;
    int lane = tid & 63, wave = tid >> 6;
    int wm = (wave >> 1) * 32, wn = (wave & 1) * 32;
    int mBase = blockIdx.x * 64, nBase = blockIdx.y * 64;
    int lr = lane & 15, lg = lane >> 4;

    const f4v fz = {0.f, 0.f, 0.f, 0.f};
    f4v acc[2][2];
    acc[0][0] = fz; acc[0][1] = fz; acc[1][0] = fz; acc[1][1] = fz;

    int ar = tid >> 2, ac = (tid & 3) * 16;
    int br = tid >> 2, bc = (tid & 3) * 16;

    for (int kb = 0; kb < K; kb += 64) {
        const short8* ag = (const short8*)(A + (size_t)(mBase + ar) * K + kb + ac);
        *(short8*)&As[ar][ac]     = ag[0];
        *(short8*)&As[ar][ac + 8] = ag[1];
        if constexpr (EPI == 3) {
            #pragma unroll
            for (int j = 0; j < 16; ++j) {
                int col = nBase + bc + j;
                float f = (col < N) ? B[(size_t)(kb + br) * N + col] : 0.f;
                Bs[bc + j][br] = f2bf(f);
            }
        } else {
            const float4* bg = (const float4*)(B + (size_t)(kb + br) * N + nBase + bc);
            float fv[16];
            *(float4*)&fv[0]  = bg[0];
            *(float4*)&fv[4]  = bg[1];
            *(float4*)&fv[8]  = bg[2];
            *(float4*)&fv[12] = bg[3];
            #pragma unroll
            for (int j = 0; j < 16; ++j) Bs[bc + j][br] = f2bf(fv[j]);
        }
        __syncthreads();
        #pragma unroll
        for (int kk = 0; kk < 2; ++kk) {
            short8 a0 = *(const short8*)&As[wm + lr][kk * 32 + lg * 8];
            short8 a1 = *(const short8*)&As[wm + 16 + lr][kk * 32 + lg * 8];
            short8 b0 = *(const short8*)&Bs[wn + lr][kk * 32 + lg * 8];
            short8 b1 = *(const short8*)&Bs[wn + 16 + lr][kk * 32 + lg * 8];
            acc[0][0] = __builtin_amdgcn_mfma_f32_16x16x32_bf16(a0, b0, acc[0][0], 0, 0, 0);
            acc[0][1] = __builtin_amdgcn_mfma_f32_16x16x32_bf16(a0, b1, acc[0][1], 0, 0, 0);
            acc[1][0] = __builtin_amdgcn_mfma_f32_16x16x32_bf16(a1, b0, acc[1][0], 0, 0, 0);
            acc[1][1] = __builtin_amdgcn_mfma_f32_16x16x32_bf16(a1, b1, acc[1][1], 0, 0, 0);
        }
        __syncthreads();
    }

    #pragma unroll
    for (int fm = 0; fm < 2; ++fm)
        #pragma unroll
        for (int fn = 0; fn < 2; ++fn)
            #pragma unroll
            for (int r = 0; r < 4; ++r) {
                int row = mBase + wm + fm * 16 + 4 * lg + r;
                int col = nBase + wn + fn * 16 + lr;
                float v = acc[fm][fn][r];
                if constexpr (EPI == 0) {
                    ((ushort*)outp)[(size_t)row * N + col] = f2bf(v);
                } else if constexpr (EPI == 1) {
                    v += bias[col] + res[(size_t)row * N + col];
                    ((float*)outp)[(size_t)row * N + col] = v;
                } else if constexpr (EPI == 2) {
                    v += bias[col];
                    v = 0.5f * v * (1.f + erff(v * 0.70710678118f));
                    ((ushort*)outp)[(size_t)row * N + col] = f2bf(v);
                } else {
                    if (col < N) ((float*)outp)[(size_t)row * N + col] = v;
                }
            }
}

__global__ __launch_bounds__(256) void attn_stage(const ushort* __restrict__ Qg,
                                                  const ushort* __restrict__ Kg,
                                                  const ushort* __restrict__ Vg,
                                                  ushort* __restrict__ Og,
                                                  int ld) {
    __shared__ ushort Ks[64][64];
    __shared__ ushort Vs[64][72];
    __shared__ ushort Ps[4][16][64];
    int tid = threadIdx.x, lane = tid & 63, wave = tid >> 6;
    int qb = blockIdx.x, head = blockIdx.y;
    int lr = lane & 15, lg = lane >> 4;
    int qr0 = qb * 64 + wave * 16;
    size_t hoff = (size_t)head * HDM;

    short8 qf0 = *(const short8*)(Qg + (size_t)(qr0 + lr) * ld + hoff + lg * 8);
    short8 qf1 = *(const short8*)(Qg + (size_t)(qr0 + lr) * ld + hoff + 32 + lg * 8);

    const f4v fz = {0.f, 0.f, 0.f, 0.f};
    f4v o[4];
    o[0] = fz; o[1] = fz; o[2] = fz; o[3] = fz;
    float mrow[4] = {-1e30f, -1e30f, -1e30f, -1e30f};
    float lsum[4] = {0.f, 0.f, 0.f, 0.f};

    int r_ = tid >> 2, c_ = (tid & 3) * 16;

    for (int kb = 0; kb <= qb; ++kb) {
        const short8* kg = (const short8*)(Kg + (size_t)(kb * 64 + r_) * ld + hoff + c_);
        *(short8*)&Ks[r_][c_]     = kg[0];
        *(short8*)&Ks[r_][c_ + 8] = kg[1];
        const short8* vg = (const short8*)(Vg + (size_t)(kb * 64 + r_) * ld + hoff + c_);
        short8 v0 = vg[0], v1 = vg[1];
        #pragma unroll
        for (int j = 0; j < 8; ++j) {
            Vs[c_ + j][r_]     = (ushort)v0[j];
            Vs[c_ + 8 + j][r_] = (ushort)v1[j];
        }
        __syncthreads();

        f4v s[4];
        #pragma unroll
        for (int n = 0; n < 4; ++n) {
            short8 k0 = *(const short8*)&Ks[n * 16 + lr][lg * 8];
            short8 k1 = *(const short8*)&Ks[n * 16 + lr][32 + lg * 8];
            f4v z = fz;
            z = __builtin_amdgcn_mfma_f32_16x16x32_bf16(qf0, k0, z, 0, 0, 0);
            s[n] = __builtin_amdgcn_mfma_f32_16x16x32_bf16(qf1, k1, z, 0, 0, 0);
        }
        if (kb == qb) {
            #pragma unroll
            for (int n = 0; n < 4; ++n)
                #pragma unroll
                for (int r = 0; r < 4; ++r) {
                    int col = kb * 64 + n * 16 + lr;
                    int row = qr0 + 4 * lg + r;
                    if (col > row) s[n][r] = -1e38f;
                }
        }

        #pragma unroll
        for (int r = 0; r < 4; ++r) {
            float mx = fmaxf(fmaxf(s[0][r], s[1][r]), fmaxf(s[2][r], s[3][r]));
            mx = fmaxf(mx, __shfl_xor(mx, 1));
            mx = fmaxf(mx, __shfl_xor(mx, 2));
            mx = fmaxf(mx, __shfl_xor(mx, 4));
            mx = fmaxf(mx, __shfl_xor(mx, 8));
            float mnew = fmaxf(mrow[r], mx);
            float corr = __expf(mrow[r] - mnew);
            float ps0 = __expf(s[0][r] - mnew);
            float ps1 = __expf(s[1][r] - mnew);
            float ps2 = __expf(s[2][r] - mnew);
            float ps3 = __expf(s[3][r] - mnew);
            float rs = ps0 + ps1 + ps2 + ps3;
            rs += __shfl_xor(rs, 1);
            rs += __shfl_xor(rs, 2);
            rs += __shfl_xor(rs, 4);
            rs += __shfl_xor(rs, 8);
            lsum[r] = lsum[r] * corr + rs;
            mrow[r] = mnew;
            o[0][r] *= corr; o[1][r] *= corr; o[2][r] *= corr; o[3][r] *= corr;
            Ps[wave][4 * lg + r][0 * 16 + lr] = f2bf(ps0);
            Ps[wave][4 * lg + r][1 * 16 + lr] = f2bf(ps1);
            Ps[wave][4 * lg + r][2 * 16 + lr] = f2bf(ps2);
            Ps[wave][4 * lg + r][3 * 16 + lr] = f2bf(ps3);
        }
        __syncthreads();

        #pragma unroll
        for (int kk = 0; kk < 2; ++kk) {
            short8 pa = *(const short8*)&Ps[wave][lr][kk * 32 + lg * 8];
            #pragma unroll
            for (int dn = 0; dn < 4; ++dn) {
                short8 vb = *(const short8*)&Vs[dn * 16 + lr][kk * 32 + lg * 8];
                o[dn] = __builtin_amdgcn_mfma_f32_16x16x32_bf16(pa, vb, o[dn], 0, 0, 0);
            }
        }
        __syncthreads();
    }

    #pragma unroll
    for (int dn = 0; dn < 4; ++dn)
        #pragma unroll
        for (int r = 0; r < 4; ++r) {
            int row = qr0 + 4 * lg + r;
            Og[(size_t)row * DM + hoff + dn * 16 + lr] = f2bf(o[dn][r] / lsum[r]);
        }
}

extern "C" void kernel_launch(void* const* d_in, const int* in_sizes, int n_in,
                              void* d_out, int out_size, void* d_ws, size_t ws_size,
                              hipStream_t stream) {
    const float* x     = (const float*)d_in[0];
    const float* ln1_g = (const float*)d_in[1];
    const float* ln1_b = (const float*)d_in[2];
    const float* Wq    = (const float*)d_in[3];
    const float* Wk    = (const float*)d_in[4];
    const float* Wv    = (const float*)d_in[5];
    const float* Wo    = (const float*)d_in[6];
    const float* bo    = (const float*)d_in[7];
    const float* ln2_g = (const float*)d_in[8];
    const float* ln2_b = (const float*)d_in[9];
    const float* Wfc   = (const float*)d_in[10];
    const float* bfc   = (const float*)d_in[11];
    const float* Wp    = (const float*)d_in[12];
    const float* bp    = (const float*)d_in[13];
    const float* lnf_g = (const float*)d_in[14];
    const float* lnf_b = (const float*)d_in[15];
    const float* Wlm   = (const float*)d_in[16];

    dim3 blk(256);

    // ---- workspace layout (new path) ----
    size_t offs[13];
    size_t need = 0;
    size_t sizes[12] = {
        (size_t)SEQ * DM * 4,          // h (fp32)
        (size_t)SEQ * DM * 2,          // hn
        (size_t)SEQ * 2304 * 2,        // qkv packed
        (size_t)SEQ * DM * 2,          // ab
        (size_t)SEQ * FF * 2,          // fb
        (size_t)DM * SEQ * 2,          // vT [768][2048]
        (size_t)NL * 2304 * DM * 2,    // qkvw^T packed
        (size_t)NL * DM * DM * 2,      // Wo^T
        (size_t)NL * FF * DM * 2,      // Wfc^T
        (size_t)NL * DM * FF * 2,      // Wp^T
        (size_t)NVP * DM * 2,          // Wlm^T [50496][768]
        (size_t)4 * SEQ * DM * 4,      // spk: split-K partials (25 MB)
    };
    for (int i = 0; i < 12; ++i) { offs[i] = need; need += sizes[i]; }
    offs[12] = need;
    size_t need_base = offs[11];       // without spk
    bool useSpk = (ws_size >= need);

    if (ws_size >= need_base) {
        char* ws = (char*)d_ws;
        float*  h    = (float*)(ws + offs[0]);
        ushort* hn   = (ushort*)(ws + offs[1]);
        ushort* qkv  = (ushort*)(ws + offs[2]);
        ushort* ab_  = (ushort*)(ws + offs[3]);
        ushort* fb_  = (ushort*)(ws + offs[4]);
        ushort* vt   = (ushort*)(ws + offs[5]);
        ushort* qkvw = (ushort*)(ws + offs[6]);
        ushort* wow  = (ushort*)(ws + offs[7]);
        ushort* fcw  = (ushort*)(ws + offs[8]);
        ushort* wpw  = (ushort*)(ws + offs[9]);
        ushort* lmw  = (ushort*)(ws + offs[10]);
        float*  spk  = (float*)(ws + offs[11]);

        hipMemcpyAsync(h, x, (size_t)SEQ * DM * 4, hipMemcpyDeviceToDevice, stream);

        // ---- single merged weight-conversion dispatch ----
        CvtArgs ca;
        const float* srcs[7] = {Wq, Wk, Wv, Wo, Wfc, Wp, Wlm};
        ushort* dsts[7] = {qkvw, qkvw + DM * DM, qkvw + 2 * DM * DM, wow, fcw, wpw, lmw};
        long inLs[7]  = {(long)DM * DM, (long)DM * DM, (long)DM * DM, (long)DM * DM,
                         (long)DM * FF, (long)FF * DM, 0};
        long outLs[7] = {(long)2304 * DM, (long)2304 * DM, (long)2304 * DM, (long)DM * DM,
                         (long)FF * DM, (long)DM * FF, 0};
        int Ks_[7] = {DM, DM, DM, DM, DM, FF, DM};
        int Ns_[7] = {DM, DM, DM, DM, FF, DM, NV};
        int tks[7] = {12, 12, 12, 12, 12, 48, 12};
        int tns[7] = {12, 12, 12, 12, 48, 12, NVP / 64};
        int lays[7] = {NL, NL, NL, NL, NL, NL, 1};
        int total = 0;
        for (int i = 0; i < 7; ++i) {
            ca.src[i] = srcs[i]; ca.dst[i] = dsts[i];
            ca.inL[i] = inLs[i]; ca.outL[i] = outLs[i];
            ca.K[i] = Ks_[i]; ca.N[i] = Ns_[i]; ca.tk[i] = tks[i]; ca.tn[i] = tns[i];
            ca.base[i] = total;
            total += tks[i] * tns[i] * lays[i];
        }
        ca.base[7] = total;
        cvt_all<<<dim3(total), blk, 0, stream>>>(ca);

        ln_kernel<<<SEQ, blk, 0, stream>>>(h, ln1_g, ln1_b, hn);
        for (int l = 0; l < NL; ++l) {
            const ushort* qw = qkvw + (size_t)l * 2304 * DM;
            gemmT<64, 64, 4, true, false, 2><<<dim3(32, 36), blk, 0, stream>>>(hn, qw, nullptr, nullptr, qkv, vt, SEQ, 2304, DM, DM, 2304);
            attn_v9<<<dim3((SEQ / 32) * NH), dim3(128), 0, stream>>>(qkv, qkv + 768, vt, ab_);
            if (useSpk) {
                gemmT<64, 64, 3, true, false, 2><<<dim3(32, 12, 2), blk, 0, stream>>>(ab_, wow + (size_t)l * DM * DM, nullptr, nullptr, spk, nullptr, SEQ, DM, DM, DM / 2, DM);
                ln_spk<2><<<SEQ, blk, 0, stream>>>(spk, bo + l * DM, h, ln2_g + l * DM, ln2_b + l * DM, hn);
            } else {
                gemmT<64, 64, 1, true, false, 2><<<dim3(32, 12), blk, 0, stream>>>(ab_, wow + (size_t)l * DM * DM, bo + l * DM, h, h, nullptr, SEQ, DM, DM, DM, DM);
                ln_kernel<<<SEQ, blk, 0, stream>>>(h, ln2_g + l * DM, ln2_b + l * DM, hn);
            }
            gemmT<64, 64, 2, true, false, 2><<<dim3(32, 48), blk, 0, stream>>>(hn, fcw + (size_t)l * FF * DM, bfc + l * FF, nullptr, fb_, nullptr, SEQ, FF, DM, DM, FF);
            const float* g2 = (l + 1 < NL) ? ln1_g + (l + 1) * DM : lnf_g;
            const float* b2 = (l + 1 < NL) ? ln1_b + (l + 1) * DM : lnf_b;
            if (useSpk) {
                gemmT<64, 64, 3, true, false, 2><<<dim3(32, 12, 4), blk, 0, stream>>>(fb_, wpw + (size_t)l * DM * FF, nullptr, nullptr, spk, nullptr, SEQ, DM, FF, FF / 4, DM);
                ln_spk<4><<<SEQ, blk, 0, stream>>>(spk, bp + l * DM, h, g2, b2, hn);
            } else {
                gemmT<64, 64, 1, true, false, 2><<<dim3(32, 12), blk, 0, stream>>>(fb_, wpw + (size_t)l * DM * FF, bp + l * DM, h, h, nullptr, SEQ, DM, FF, FF, DM);
                ln_kernel<<<SEQ, blk, 0, stream>>>(h, g2, b2, hn);
            }
        }
        gemmT<128, 192, 3, false, true, 3><<<dim3(16, NVP / 192), blk, 0, stream>>>(hn, lmw, nullptr, nullptr, d_out, nullptr, SEQ, NV, DM, DM, NV);
        return;
    }

    // ---------------- fallback: round-1 path (fp32-B GEMMs) ----------------
    char* ws = (char*)d_ws;
    float*  h   = (float*)ws;   ws += (size_t)SEQ * DM * 4;
    ushort* hn  = (ushort*)ws;  ws += (size_t)SEQ * DM * 2;
    ushort* qb_ = (ushort*)ws;  ws += (size_t)SEQ * DM * 2;
    ushort* kb_ = (ushort*)ws;  ws += (size_t)SEQ * DM * 2;
    ushort* vb_ = (ushort*)ws;  ws += (size_t)SEQ * DM * 2;
    ushort* ab_ = (ushort*)ws;  ws += (size_t)SEQ * DM * 2;
    ushort* fb_ = (ushort*)ws;  ws += (size_t)SEQ * FF * 2;

    hipMemcpyAsync(h, x, (size_t)SEQ * DM * 4, hipMemcpyDeviceToDevice, stream);

    dim3 gdd(SEQ / 64, DM / 64);
    dim3 gdf(SEQ / 64, FF / 64);
    dim3 gda(SEQ / 64, NH);
    dim3 gdl(SEQ / 64, (NV + 63) / 64);

    for (int l = 0; l < NL; ++l) {
        ln_kernel<<<SEQ, blk, 0, stream>>>(h, ln1_g + l * DM, ln1_b + l * DM, hn);
        gemm64<0><<<gdd, blk, 0, stream>>>(hn, Wq + (size_t)l * DM * DM, nullptr, nullptr, qb_, SEQ, DM, DM);
        gemm64<0><<<gdd, blk, 0, stream>>>(hn, Wk + (size_t)l * DM * DM, nullptr, nullptr, kb_, SEQ, DM, DM);
        gemm64<0><<<gdd, blk, 0, stream>>>(hn, Wv + (size_t)l * DM * DM, nullptr, nullptr, vb_, SEQ, DM, DM);
        attn_stage<<<gda, blk, 0, stream>>>(qb_, kb_, vb_, ab_, DM);
        gemm64<1><<<gdd, blk, 0, stream>>>(ab_, Wo + (size_t)l * DM * DM, bo + l * DM, h, h, SEQ, DM, DM);
        ln_kernel<<<SEQ, blk, 0, stream>>>(h, ln2_g + l * DM, ln2_b + l * DM, hn);
        gemm64<2><<<gdf, blk, 0, stream>>>(hn, Wfc + (size_t)l * DM * FF, bfc + l * FF, nullptr, fb_, SEQ, FF, DM);
        gemm64<1><<<gdd, blk, 0, stream>>>(fb_, Wp + (size_t)l * FF * DM, bp + l * DM, h, h, SEQ, DM, FF);
    }
    ln_kernel<<<SEQ, blk, 0, stream>>>(h, lnf_g, lnf_b, hn);
    gemm64<3><<<gdl, blk, 0, stream>>>(hn, Wlm, nullptr, nullptr, d_out, SEQ, NV, DM);
}